// Round 15
// baseline (300.020 us; speedup 1.0000x reference)
//
#include <hip/hip_runtime.h>
#include <hip/hip_bf16.h>

#define B   2
#define NN_ 5000
#define NE_ 160000
#define F   128
#define HID 128
#define ED  16

typedef __bf16 bf16x8 __attribute__((ext_vector_type(8)));
typedef __bf16 bf16x4 __attribute__((ext_vector_type(4)));
typedef float  f32x4  __attribute__((ext_vector_type(4)));

#define MS  136   // edge buf row stride (17 16B-units, odd -> conflict-free b128)
#define PS  40    // xs32 row stride
#define EDG 64    // edges per block
#define ZS  264   // node z row stride bf16
#define HS  136   // node h1 row stride
#define NPB2 32   // nodes per block
#define NBUCKET 313  // bucket blocks in mid_kernel (313*512 >= NE_)

// ------ pack weights (+ zero agg/csr_cnt: replaces two memsets) ------
// frag: lane l holds W[k = kt*32 + (l>>4)*8 + j][n = nt*16 + (l&15)]; used as
// A-operand (W^T): D = W^T x X^T -> D[feat][edge] (col=edge, row=quad*4+i).
__global__ void pack_weights(const float* __restrict__ We1, const float* __restrict__ We2,
                             const float* __restrict__ Wc1, const float* __restrict__ Wc2,
                             const float* __restrict__ Wn1, const float* __restrict__ Wn2,
                             __bf16* __restrict__ pw1, __bf16* __restrict__ pw2,
                             __bf16* __restrict__ pwc1, __bf16* __restrict__ pwc2,
                             __bf16* __restrict__ pwn1, __bf16* __restrict__ pwn2,
                             float4* __restrict__ agg4, int* __restrict__ csr_cnt)
{
    int idx = blockIdx.x * 256 + threadIdx.x;   // 0 .. 120831
    const float* W; __bf16* P; int KT, Nr, local;
    if (idx < 36864)       { W = We1; P = pw1;  KT = 9; Nr = 128; local = idx; }
    else if (idx < 53248)  { W = We2; P = pw2;  KT = 4; Nr = 128; local = idx - 36864; }
    else if (idx < 69632)  { W = Wc1; P = pwc1; KT = 4; Nr = 128; local = idx - 53248; }
    else if (idx < 71680)  { W = Wc2; P = pwc2; KT = 4; Nr = 4;   local = idx - 69632; }
    else if (idx < 104448) { W = Wn1; P = pwn1; KT = 8; Nr = 128; local = idx - 71680; }
    else                   { W = Wn2; P = pwn2; KT = 4; Nr = 128; local = idx - 104448; }
    int j = local & 7, lane = (local >> 3) & 63, rest = local >> 9;
    int kt = rest % KT, nt = rest / KT;
    int k = kt * 32 + (lane >> 4) * 8 + j;
    int n = nt * 16 + (lane & 15);
    float v = (n < Nr) ? W[k * Nr + n] : 0.f;
    P[local] = (__bf16)v;

    // zero agg_h+agg_c (contiguous, 350000 float4) and csr_cnt
    float4 z4 = {0.f, 0.f, 0.f, 0.f};
    for (int i = idx; i < 350000; i += 120832) agg4[i] = z4;
    if (idx < NN_) csr_cnt[idx] = 0;
}

// ---------------- CSR build ----------------
__global__ void hist_kernel(const int* __restrict__ ei, int* __restrict__ csr_cnt)
{
    int i = blockIdx.x * 256 + threadIdx.x;
    if (i < NE_) atomicAdd(&csr_cnt[ei[i]], 1);
}

__global__ __launch_bounds__(512) void scan_kernel(const int* __restrict__ csr_cnt,
                                                   int* __restrict__ csr_off, int* __restrict__ csr_pos)
{
    __shared__ int part[512];
    const int t = threadIdx.x;
    int sum = 0;
    #pragma unroll
    for (int j = 0; j < 10; j++) {
        int idx = t * 10 + j;
        if (idx < NN_) sum += csr_cnt[idx];
    }
    part[t] = sum;
    __syncthreads();
    for (int off = 1; off < 512; off <<= 1) {
        int v = (t >= off) ? part[t - off] : 0;
        __syncthreads();
        part[t] += v;
        __syncthreads();
    }
    int run = part[t] - sum;   // exclusive base of this thread's chunk
    #pragma unroll
    for (int j = 0; j < 10; j++) {
        int idx = t * 10 + j;
        if (idx < NN_) { csr_off[idx] = run; csr_pos[idx] = run; run += csr_cnt[idx]; }
    }
    if (t == 0) csr_off[NN_] = NE_;
}

// ------ mid kernel: bucket blocks || pre (P_r/P_c GEMM) blocks ------
__global__ __launch_bounds__(512) void mid_kernel(
    const int* __restrict__ ei,
    int* __restrict__ csr_pos, int* __restrict__ bucket,
    const float* __restrict__ h, const __bf16* __restrict__ pw1,
    __bf16* __restrict__ pr, __bf16* __restrict__ pc)
{
    __shared__ __align__(16) __bf16 hs[128 * MS];
    const int t = threadIdx.x;

    if (blockIdx.x < NBUCKET) {
        int i = blockIdx.x * 512 + t;
        if (i < NE_) {
            int p = atomicAdd(&csr_pos[ei[i]], 1);
            bucket[p] = i;
        }
        return;
    }

    const int bp = blockIdx.x - NBUCKET;      // 0..79
    const int b = bp / 40;
    const int n0 = (bp % 40) * 128;
    const int lane = t & 63, wave = t >> 6;   // wave = nt (8 feat-tiles)
    const int quad = lane >> 4, c = lane & 15;

    #pragma unroll
    for (int it = 0; it < 8; it++) {
        int idx = it * 512 + t;               // 0..4095
        int node = idx >> 5, ch = idx & 31;
        int gn = n0 + node;
        float4 v = (gn < NN_) ? *(const float4*)&h[((size_t)b * NN_ + gn) * F + ch * 4]
                              : (float4){0.f, 0.f, 0.f, 0.f};
        bf16x4 bv = {(__bf16)v.x, (__bf16)v.y, (__bf16)v.z, (__bf16)v.w};
        *(bf16x4*)&hs[node * MS + ch * 4] = bv;
    }
    __syncthreads();

    const bf16x8* pw1v = (const bf16x8*)pw1;
    f32x4 accr[8], accc[8];
    #pragma unroll
    for (int m = 0; m < 8; m++) { accr[m] = (f32x4){0,0,0,0}; accc[m] = (f32x4){0,0,0,0}; }
    for (int kt = 0; kt < 4; kt++) {
        bf16x8 wr = pw1v[(wave * 9 + kt) * 64 + lane];       // We1 rows 0..127
        bf16x8 wc = pw1v[(wave * 9 + kt + 4) * 64 + lane];   // We1 rows 128..255
        #pragma unroll
        for (int m = 0; m < 8; m++) {
            bf16x8 x = *(const bf16x8*)&hs[(m * 16 + c) * MS + kt * 32 + quad * 8];
            accr[m] = __builtin_amdgcn_mfma_f32_16x16x32_bf16(wr, x, accr[m], 0, 0, 0);
            accc[m] = __builtin_amdgcn_mfma_f32_16x16x32_bf16(wc, x, accc[m], 0, 0, 0);
        }
    }
    #pragma unroll
    for (int m = 0; m < 8; m++) {
        int gn = n0 + m * 16 + c;
        if (gn < NN_) {
            size_t base = ((size_t)b * NN_ + gn) * F + wave * 16 + quad * 4;
            bf16x4 orr = {(__bf16)accr[m][0], (__bf16)accr[m][1], (__bf16)accr[m][2], (__bf16)accr[m][3]};
            bf16x4 occ = {(__bf16)accc[m][0], (__bf16)accc[m][1], (__bf16)accc[m][2], (__bf16)accc[m][3]};
            *(bf16x4*)&pr[base] = orr;
            *(bf16x4*)&pc[base] = occ;
        }
    }
}

// ------- edge kernel: batch-merged (loop b), staged-presum e1, MFMA chain, seg-reduce -------
// wave owns nt pair {2*wave, 2*wave+1}; m loops all 4 edge m-tiles.
__global__ __launch_bounds__(256, 4) void edge_kernel(
    const __bf16* __restrict__ pr, const __bf16* __restrict__ pc,
    const float* __restrict__ coord,
    const int* __restrict__ ei, const float* __restrict__ ea,
    const int* __restrict__ bucket,
    const float* __restrict__ be1, const float* __restrict__ be2,
    const float* __restrict__ bc1,
    const __bf16* __restrict__ pw1, const __bf16* __restrict__ pw2,
    const __bf16* __restrict__ pwc1, const __bf16* __restrict__ pwc2,
    float* __restrict__ agg_h, float* __restrict__ agg_c)
{
    __shared__ __align__(16) __bf16 buf1[EDG * MS];  // presum -> h1 -> h2
    __shared__ __align__(16) __bf16 buf2[EDG * MS];  // xs32 (stride PS) -> ef
    __shared__ __align__(16) __bf16 eastash[EDG * 16];  // ea bf16, batch-invariant
    __shared__ __bf16 cds[EDG][12];
    __shared__ int rs[EDG], cs[EDG];

    const int t = threadIdx.x;            // 0..255
    const int p0 = blockIdx.x * EDG;
    const int lane = t & 63, wave = t >> 6;
    const int quad = lane >> 4, c = lane & 15;

    if (t < EDG) {
        int eid = bucket[p0 + t];
        rs[t] = ei[eid]; cs[t] = ei[NE_ + eid];
        // ea gather once (batch-invariant)
        const float4* ep = (const float4*)(ea + (size_t)eid * ED);
        #pragma unroll
        for (int j = 0; j < 4; j++) {
            float4 v = ep[j];
            bf16x4 bv = {(__bf16)v.x, (__bf16)v.y, (__bf16)v.z, (__bf16)v.w};
            *(bf16x4*)&eastash[t * 16 + j * 4] = bv;
        }
    }
    __syncthreads();

    const bf16x8* pw1v  = (const bf16x8*)pw1;
    const bf16x8* pw2v  = (const bf16x8*)pw2;
    const bf16x8* pwc1v = (const bf16x8*)pwc1;
    const bf16x8* pwc2v = (const bf16x8*)pwc2;

    for (int b = 0; b < B; b++) {
        // ---- stage presum = pr[row] + pc[col] into buf1 (coalesced, all threads) ----
        const __bf16* prb = pr + (size_t)b * NN_ * F;
        const __bf16* pcb = pc + (size_t)b * NN_ * F;
        #pragma unroll
        for (int it = 0; it < 4; it++) {
            int idx = it * 256 + t;           // 0..1023: 64 edges x 16 chunks of 8
            int e = idx >> 4, ch = idx & 15;
            bf16x8 a = *(const bf16x8*)(prb + (size_t)rs[e] * F + ch * 8);
            bf16x8 v = *(const bf16x8*)(pcb + (size_t)cs[e] * F + ch * 8);
            bf16x8 o;
            #pragma unroll
            for (int j = 0; j < 8; j++) o[j] = (__bf16)((float)a[j] + (float)v[j]);
            *(bf16x8*)&buf1[e * MS + ch * 8] = o;
        }
        // ---- radial (per batch) + ea (from stash) -> xs32 (buf2, stride PS) ----
        if (t < EDG) {
            int e = t;
            const float* cr = coord + ((size_t)b * NN_ + rs[e]) * 12;
            const float* cc = coord + ((size_t)b * NN_ + cs[e]) * 12;
            float cd[12];
            #pragma unroll
            for (int j = 0; j < 12; j++) { cd[j] = cr[j] - cc[j]; cds[e][j] = (__bf16)cd[j]; }
            float prod[16]; float ss = 0.f;
            #pragma unroll
            for (int j = 0; j < 4; j++)
                #pragma unroll
                for (int k = 0; k < 4; k++) {
                    float p = cd[j*3]*cd[k*3] + cd[j*3+1]*cd[k*3+1] + cd[j*3+2]*cd[k*3+2];
                    prod[j*4 + k] = p; ss += p * p;
                }
            float inv = 1.0f / fmaxf(sqrtf(ss), 1e-12f);
            #pragma unroll
            for (int j = 0; j < 16; j++) buf2[e * PS + j] = (__bf16)(prod[j] * inv);
            *(uint4*)&buf2[e * PS + 16] = *(const uint4*)&eastash[e * 16];
            *(uint4*)&buf2[e * PS + 24] = *(const uint4*)&eastash[e * 16 + 8];
        }
        __syncthreads();

        // ---- e1: K=32 (kt=8 of pw1) + presum + bias ----
        f32x4 acc1[4][2];
        #pragma unroll
        for (int m = 0; m < 4; m++)
            #pragma unroll
            for (int n = 0; n < 2; n++) acc1[m][n] = (f32x4){0,0,0,0};
        {
            bf16x8 x1[4];
            #pragma unroll
            for (int m = 0; m < 4; m++)
                x1[m] = *(const bf16x8*)&buf2[(m*16 + c) * PS + quad*8];
            #pragma unroll
            for (int n = 0; n < 2; n++) {
                bf16x8 w = pw1v[((2*wave + n)*9 + 8)*64 + lane];
                #pragma unroll
                for (int m = 0; m < 4; m++)
                    acc1[m][n] = __builtin_amdgcn_mfma_f32_16x16x32_bf16(w, x1[m], acc1[m][n], 0, 0, 0);
            }
        }
        #pragma unroll
        for (int n = 0; n < 2; n++) {
            int nt = 2*wave + n;
            float4 bb = *(const float4*)&be1[nt*16 + quad*4];
            #pragma unroll
            for (int m = 0; m < 4; m++) {
                int row = m*16 + c;
                bf16x4 p = *(const bf16x4*)&buf1[row * MS + nt*16 + quad*4];
                bf16x4 o = { (__bf16)fmaxf(acc1[m][n][0] + (float)p[0] + bb.x, 0.f),
                             (__bf16)fmaxf(acc1[m][n][1] + (float)p[1] + bb.y, 0.f),
                             (__bf16)fmaxf(acc1[m][n][2] + (float)p[2] + bb.z, 0.f),
                             (__bf16)fmaxf(acc1[m][n][3] + (float)p[3] + bb.w, 0.f) };
                *(bf16x4*)&buf1[row * MS + nt*16 + quad*4] = o;
            }
        }
        __syncthreads();

        // ---- e2: h1 @ We2 -> ef (buf2, stride MS) ----
        f32x4 acc2[4][2];
        #pragma unroll
        for (int m = 0; m < 4; m++)
            #pragma unroll
            for (int n = 0; n < 2; n++) acc2[m][n] = (f32x4){0,0,0,0};
        for (int kt = 0; kt < 4; kt++) {
            bf16x8 x[4];
            #pragma unroll
            for (int m = 0; m < 4; m++)
                x[m] = *(const bf16x8*)&buf1[(m*16 + c) * MS + kt*32 + quad*8];
            #pragma unroll
            for (int n = 0; n < 2; n++) {
                bf16x8 w = pw2v[((2*wave + n)*4 + kt)*64 + lane];
                #pragma unroll
                for (int m = 0; m < 4; m++)
                    acc2[m][n] = __builtin_amdgcn_mfma_f32_16x16x32_bf16(w, x[m], acc2[m][n], 0, 0, 0);
            }
        }
        __syncthreads();
        #pragma unroll
        for (int n = 0; n < 2; n++) {
            int nt = 2*wave + n;
            float4 bb = *(const float4*)&be2[nt*16 + quad*4];
            #pragma unroll
            for (int m = 0; m < 4; m++) {
                int row = m*16 + c;
                bf16x4 o = { (__bf16)fmaxf(acc2[m][n][0] + bb.x, 0.f),
                             (__bf16)fmaxf(acc2[m][n][1] + bb.y, 0.f),
                             (__bf16)fmaxf(acc2[m][n][2] + bb.z, 0.f),
                             (__bf16)fmaxf(acc2[m][n][3] + bb.w, 0.f) };
                *(bf16x4*)&buf2[row * MS + nt*16 + quad*4] = o;
            }
        }
        __syncthreads();

        // ---- c1: ef @ Wc1 -> buf1 ----
        f32x4 acc3[4][2];
        #pragma unroll
        for (int m = 0; m < 4; m++)
            #pragma unroll
            for (int n = 0; n < 2; n++) acc3[m][n] = (f32x4){0,0,0,0};
        for (int kt = 0; kt < 4; kt++) {
            bf16x8 x[4];
            #pragma unroll
            for (int m = 0; m < 4; m++)
                x[m] = *(const bf16x8*)&buf2[(m*16 + c) * MS + kt*32 + quad*8];
            #pragma unroll
            for (int n = 0; n < 2; n++) {
                bf16x8 w = pwc1v[((2*wave + n)*4 + kt)*64 + lane];
                #pragma unroll
                for (int m = 0; m < 4; m++)
                    acc3[m][n] = __builtin_amdgcn_mfma_f32_16x16x32_bf16(w, x[m], acc3[m][n], 0, 0, 0);
            }
        }
        #pragma unroll
        for (int n = 0; n < 2; n++) {
            int nt = 2*wave + n;
            float4 bb = *(const float4*)&bc1[nt*16 + quad*4];
            #pragma unroll
            for (int m = 0; m < 4; m++) {
                int row = m*16 + c;
                bf16x4 o = { (__bf16)fmaxf(acc3[m][n][0] + bb.x, 0.f),
                             (__bf16)fmaxf(acc3[m][n][1] + bb.y, 0.f),
                             (__bf16)fmaxf(acc3[m][n][2] + bb.z, 0.f),
                             (__bf16)fmaxf(acc3[m][n][3] + bb.w, 0.f) };
                *(bf16x4*)&buf1[row * MS + nt*16 + quad*4] = o;
            }
        }
        __syncthreads();

        // ---- c2: wave owns m-tile = wave (edges wave*16..+15) ----
        f32x4 accw = (f32x4){0,0,0,0};
        for (int kt = 0; kt < 4; kt++) {
            bf16x8 x = *(const bf16x8*)&buf1[(wave*16 + c) * MS + kt*32 + quad*8];
            accw = __builtin_amdgcn_mfma_f32_16x16x32_bf16(pwc2v[kt*64 + lane], x, accw, 0, 0, 0);
        }
        if (quad == 0) {
            int e = wave*16 + c;
            #pragma unroll
            for (int j = 0; j < 12; j++)
                cds[e][j] = (__bf16)((float)cds[e][j] * accw[j/3]);
        }
        __syncthreads();

        // ---- segmented reduction (scalar u16, 128 cols x 2 segs of 32) ----
        {
            float* aggh_b = agg_h + (size_t)b * NN_ * HID;
            const int col = t & 127, seg = t >> 7;    // 2 segs x 32 edges
            float run = 0.f;
            int cur = rs[seg * 32];
            for (int e = seg * 32; e < seg * 32 + 32; e++) {
                int r = rs[e];
                float v = (float)buf2[e * MS + col];
                if (r != cur) {
                    atomicAdd(&aggh_b[(size_t)cur * HID + col], run);
                    run = 0.f; cur = r;
                }
                run += v;
            }
            atomicAdd(&aggh_b[(size_t)cur * HID + col], run);
        }
        if (t < 24) {
            float* aggc_b = agg_c + (size_t)b * NN_ * 12;
            const int j = t % 12, q = t / 12;         // 2 segs x 32 edges
            float run = 0.f;
            int cur = rs[q * 32];
            for (int e = q * 32; e < q * 32 + 32; e++) {
                int r = rs[e];
                float v = (float)cds[e][j];
                if (r != cur) {
                    atomicAdd(&aggc_b[(size_t)cur * 12 + j], run);
                    run = 0.f; cur = r;
                }
                run += v;
            }
            atomicAdd(&aggc_b[(size_t)cur * 12 + j], run);
        }
        __syncthreads();   // buf2/cds dead before next batch's staging
    }
}

// ------- node kernel: MFMA bf16 MLP + residual + fused coord update -------
__global__ __launch_bounds__(256) void node_kernel(
    const float* __restrict__ h, const float* __restrict__ agg_h,
    const float* __restrict__ agg_c, const float* __restrict__ coord,
    const int* __restrict__ csr_off,
    const __bf16* __restrict__ pwn1, const float* __restrict__ bn1,
    const __bf16* __restrict__ pwn2, const float* __restrict__ bn2,
    float* __restrict__ out_h, float* __restrict__ out_c)
{
    __shared__ __align__(16) __bf16 zs[NPB2 * ZS];   // reused as os (fp32, stride 132)
    __shared__ __align__(16) __bf16 h1s[NPB2 * HS];
    const int t = threadIdx.x;
    const int b = blockIdx.y;
    const int n0 = blockIdx.x * NPB2;
    const int lane = t & 63, wave = t >> 6;
    const int quad = lane >> 4, c = lane & 15;

    #pragma unroll
    for (int it = 0; it < 8; it++) {
        int idx = it * 256 + t;              // 0..2047
        int node = idx >> 6, ch = idx & 63;  // ch 0..31 = h, 32..63 = agg_h
        int gn = n0 + node;
        float4 v = (float4){0.f, 0.f, 0.f, 0.f};
        if (gn < NN_) {
            const float* src = (ch < 32) ? &h[((size_t)b * NN_ + gn) * F + ch * 4]
                                         : &agg_h[((size_t)b * NN_ + gn) * HID + (ch - 32) * 4];
            v = *(const float4*)src;
        }
        bf16x4 bv = {(__bf16)v.x, (__bf16)v.y, (__bf16)v.z, (__bf16)v.w};
        *(bf16x4*)&zs[node * ZS + ch * 4] = bv;
    }
    __syncthreads();

    const bf16x8* w1v = (const bf16x8*)pwn1;
    const bf16x8* w2v = (const bf16x8*)pwn2;
    f32x4 a1[2][2];
    #pragma unroll
    for (int m = 0; m < 2; m++)
        #pragma unroll
        for (int n = 0; n < 2; n++) a1[m][n] = (f32x4){0,0,0,0};
    for (int kt = 0; kt < 8; kt++) {
        bf16x8 x[2];
        #pragma unroll
        for (int m = 0; m < 2; m++)
            x[m] = *(const bf16x8*)&zs[(m*16 + c) * ZS + kt*32 + quad*8];
        #pragma unroll
        for (int n = 0; n < 2; n++) {
            bf16x8 w = w1v[((2*wave + n)*8 + kt)*64 + lane];
            #pragma unroll
            for (int m = 0; m < 2; m++)
                a1[m][n] = __builtin_amdgcn_mfma_f32_16x16x32_bf16(w, x[m], a1[m][n], 0, 0, 0);
        }
    }
    __syncthreads();
    #pragma unroll
    for (int n = 0; n < 2; n++) {
        int nt = 2*wave + n;
        float4 bb = *(const float4*)&bn1[nt*16 + quad*4];
        #pragma unroll
        for (int m = 0; m < 2; m++) {
            bf16x4 o = { (__bf16)fmaxf(a1[m][n][0] + bb.x, 0.f),
                         (__bf16)fmaxf(a1[m][n][1] + bb.y, 0.f),
                         (__bf16)fmaxf(a1[m][n][2] + bb.z, 0.f),
                         (__bf16)fmaxf(a1[m][n][3] + bb.w, 0.f) };
            *(bf16x4*)&h1s[(m*16 + c) * HS + nt*16 + quad*4] = o;
        }
    }
    __syncthreads();

    f32x4 a2[2][2];
    #pragma unroll
    for (int m = 0; m < 2; m++)
        #pragma unroll
        for (int n = 0; n < 2; n++) a2[m][n] = (f32x4){0,0,0,0};
    for (int kt = 0; kt < 4; kt++) {
        bf16x8 x[2];
        #pragma unroll
        for (int m = 0; m < 2; m++)
            x[m] = *(const bf16x8*)&h1s[(m*16 + c) * HS + kt*32 + quad*8];
        #pragma unroll
        for (int n = 0; n < 2; n++) {
            bf16x8 w = w2v[((2*wave + n)*4 + kt)*64 + lane];
            #pragma unroll
            for (int m = 0; m < 2; m++)
                a2[m][n] = __builtin_amdgcn_mfma_f32_16x16x32_bf16(w, x[m], a2[m][n], 0, 0, 0);
        }
    }
    float* os = (float*)zs;   // stride 132 floats
    #pragma unroll
    for (int n = 0; n < 2; n++) {
        int nt = 2*wave + n;
        float4 bb = *(const float4*)&bn2[nt*16 + quad*4];
        #pragma unroll
        for (int m = 0; m < 2; m++) {
            f32x4 o = { a2[m][n][0] + bb.x, a2[m][n][1] + bb.y,
                        a2[m][n][2] + bb.z, a2[m][n][3] + bb.w };
            *(f32x4*)&os[(m*16 + c) * 132 + nt*16 + quad*4] = o;
        }
    }
    __syncthreads();

    #pragma unroll
    for (int it = 0; it < 4; it++) {
        int idx = it * 256 + t;              // 0..1023
        int node = idx >> 5, ch = idx & 31;
        int gn = n0 + node;
        if (gn < NN_) {
            size_t gb = ((size_t)b * NN_ + gn) * F + ch * 4;
            float4 hres = *(const float4*)&h[gb];
            float4 acc = *(const float4*)&os[node * 132 + ch * 4];
            float4 o = { hres.x + acc.x, hres.y + acc.y, hres.z + acc.z, hres.w + acc.w };
            *(float4*)&out_h[gb] = o;
        }
    }
    for (int idx = t; idx < NPB2 * 12; idx += 256) {
        int node = idx / 12, j = idx % 12;
        int gn = n0 + node;
        if (gn < NN_) {
            float deg = (float)(csr_off[gn + 1] - csr_off[gn]);
            size_t ci = ((size_t)b * NN_ + gn) * 12 + j;
            out_c[ci] = coord[ci] + agg_c[ci] / fmaxf(deg, 1.0f);
        }
    }
}

extern "C" void kernel_launch(void* const* d_in, const int* in_sizes, int n_in,
                              void* d_out, int out_size, void* d_ws, size_t ws_size,
                              hipStream_t stream) {
    const float* h     = (const float*)d_in[0];
    const float* coord = (const float*)d_in[1];
    const int*   ei    = (const int*)d_in[2];
    const float* ea    = (const float*)d_in[3];
    const float* We1   = (const float*)d_in[4];
    const float* be1   = (const float*)d_in[5];
    const float* We2   = (const float*)d_in[6];
    const float* be2   = (const float*)d_in[7];
    const float* Wn1   = (const float*)d_in[8];
    const float* bn1   = (const float*)d_in[9];
    const float* Wn2   = (const float*)d_in[10];
    const float* bn2   = (const float*)d_in[11];
    const float* Wc1   = (const float*)d_in[12];
    const float* bc1   = (const float*)d_in[13];
    const float* Wc2   = (const float*)d_in[14];

    float* out_h = (float*)d_out;                       // [B,N,F]
    float* out_c = out_h + (size_t)B * NN_ * F;         // [B,N,4,3]

    unsigned char* base = (unsigned char*)d_ws;
    __bf16* pw1  = (__bf16*)base;             // 36864 bf16
    __bf16* pw2  = pw1 + 36864;               // 16384
    __bf16* pwc1 = pw2 + 16384;               // 16384
    __bf16* pwc2 = pwc1 + 16384;              // 2048
    __bf16* pwn1 = pwc2 + 2048;               // 32768
    __bf16* pwn2 = pwn1 + 32768;              // 16384  -> 120832 elems = 241664 B
    unsigned char* dyn = base + 241664;

    int* csr_cnt = (int*)(dyn);               // 20000 B
    int* csr_off = (int*)(dyn + 20000);       // 20016 B
    int* csr_pos = (int*)(dyn + 40016);       // 20000 B
    int* bucket  = (int*)(dyn + 60016);       // 640000 B
    float* agg_h = (float*)(dyn + 700016);    // [B,N,HID]  5,120,000 B
    float* agg_c = agg_h + (size_t)B * NN_ * HID;      // [B,N,12] 480,000 B
    __bf16* pr   = (__bf16*)(agg_c + (size_t)B * NN_ * 12);  // 2,560,000 B
    __bf16* pc   = pr + (size_t)B * NN_ * F;                 // 2,560,000 B

    pack_weights<<<472, 256, 0, stream>>>(We1, We2, Wc1, Wc2, Wn1, Wn2,
                                          pw1, pw2, pwc1, pwc2, pwn1, pwn2,
                                          (float4*)agg_h, csr_cnt);

    hist_kernel<<<625, 256, 0, stream>>>(ei, csr_cnt);
    scan_kernel<<<1, 512, 0, stream>>>(csr_cnt, csr_off, csr_pos);

    mid_kernel<<<NBUCKET + 80, 512, 0, stream>>>(ei, csr_pos, bucket, h, pw1, pr, pc);

    edge_kernel<<<NE_ / EDG, 256, 0, stream>>>(pr, pc, coord, ei, ea, bucket,
                                               be1, be2, bc1,
                                               pw1, pw2, pwc1, pwc2, agg_h, agg_c);

    dim3 ng((NN_ + NPB2 - 1) / NPB2, B);   // 157 x 2
    node_kernel<<<ng, 256, 0, stream>>>(h, agg_h, agg_c, coord, csr_off,
                                        pwn1, bn1, pwn2, bn2, out_h, out_c);
}

// Round 16
// 200.069 us; speedup vs baseline: 1.4996x; 1.4996x over previous
//
#include <hip/hip_runtime.h>
#include <hip/hip_bf16.h>

#define B   2
#define NN_ 5000
#define NE_ 160000
#define F   128
#define HID 128
#define ED  16

typedef __bf16 bf16x8 __attribute__((ext_vector_type(8)));
typedef __bf16 bf16x4 __attribute__((ext_vector_type(4)));
typedef float  f32x4  __attribute__((ext_vector_type(4)));

#define MS  136   // edge buf row stride (17 16B-units, odd -> conflict-free b128)
#define PS  40    // xs32 row stride
#define EDG 64    // edges per block
#define ZS  264   // node z row stride bf16
#define HS  136   // node h1 row stride
#define NPB2 32   // nodes per block
#define NBUCKET 313  // bucket blocks in mid_kernel (313*512 >= NE_)

// ------ pack weights (+ zero agg/csr_cnt: replaces two memsets) ------
// frag: lane l holds W[k = kt*32 + (l>>4)*8 + j][n = nt*16 + (l&15)]; used as
// A-operand (W^T): D = W^T x X^T -> D[feat][edge] (col=edge, row=quad*4+i).
__global__ void pack_weights(const float* __restrict__ We1, const float* __restrict__ We2,
                             const float* __restrict__ Wc1, const float* __restrict__ Wc2,
                             const float* __restrict__ Wn1, const float* __restrict__ Wn2,
                             __bf16* __restrict__ pw1, __bf16* __restrict__ pw2,
                             __bf16* __restrict__ pwc1, __bf16* __restrict__ pwc2,
                             __bf16* __restrict__ pwn1, __bf16* __restrict__ pwn2,
                             float4* __restrict__ agg4, int* __restrict__ csr_cnt)
{
    int idx = blockIdx.x * 256 + threadIdx.x;   // 0 .. 120831
    const float* W; __bf16* P; int KT, Nr, local;
    if (idx < 36864)       { W = We1; P = pw1;  KT = 9; Nr = 128; local = idx; }
    else if (idx < 53248)  { W = We2; P = pw2;  KT = 4; Nr = 128; local = idx - 36864; }
    else if (idx < 69632)  { W = Wc1; P = pwc1; KT = 4; Nr = 128; local = idx - 53248; }
    else if (idx < 71680)  { W = Wc2; P = pwc2; KT = 4; Nr = 4;   local = idx - 69632; }
    else if (idx < 104448) { W = Wn1; P = pwn1; KT = 8; Nr = 128; local = idx - 71680; }
    else                   { W = Wn2; P = pwn2; KT = 4; Nr = 128; local = idx - 104448; }
    int j = local & 7, lane = (local >> 3) & 63, rest = local >> 9;
    int kt = rest % KT, nt = rest / KT;
    int k = kt * 32 + (lane >> 4) * 8 + j;
    int n = nt * 16 + (lane & 15);
    float v = (n < Nr) ? W[k * Nr + n] : 0.f;
    P[local] = (__bf16)v;

    // zero agg_h+agg_c (contiguous, 350000 float4) and csr_cnt
    float4 z4 = {0.f, 0.f, 0.f, 0.f};
    for (int i = idx; i < 350000; i += 120832) agg4[i] = z4;
    if (idx < NN_) csr_cnt[idx] = 0;
}

// ---------------- CSR build (hist also emits bf16 ea) ----------------
__global__ void hist_kernel(const int* __restrict__ ei, const float* __restrict__ ea,
                            int* __restrict__ csr_cnt, __bf16* __restrict__ eab)
{
    int i = blockIdx.x * 256 + threadIdx.x;
    if (i < NE_) {
        atomicAdd(&csr_cnt[ei[i]], 1);
        const float4* src = (const float4*)(ea + (size_t)i * ED);
        __bf16* dst = eab + (size_t)i * ED;
        #pragma unroll
        for (int j = 0; j < 4; j++) {
            float4 v = src[j];
            bf16x4 bv = {(__bf16)v.x, (__bf16)v.y, (__bf16)v.z, (__bf16)v.w};
            *(bf16x4*)&dst[j * 4] = bv;
        }
    }
}

__global__ __launch_bounds__(512) void scan_kernel(const int* __restrict__ csr_cnt,
                                                   int* __restrict__ csr_off, int* __restrict__ csr_pos)
{
    __shared__ int part[512];
    const int t = threadIdx.x;
    int sum = 0;
    #pragma unroll
    for (int j = 0; j < 10; j++) {
        int idx = t * 10 + j;
        if (idx < NN_) sum += csr_cnt[idx];
    }
    part[t] = sum;
    __syncthreads();
    for (int off = 1; off < 512; off <<= 1) {
        int v = (t >= off) ? part[t - off] : 0;
        __syncthreads();
        part[t] += v;
        __syncthreads();
    }
    int run = part[t] - sum;   // exclusive base of this thread's chunk
    #pragma unroll
    for (int j = 0; j < 10; j++) {
        int idx = t * 10 + j;
        if (idx < NN_) { csr_off[idx] = run; csr_pos[idx] = run; run += csr_cnt[idx]; }
    }
    if (t == 0) csr_off[NN_] = NE_;
}

// ------ mid kernel: bucket blocks || pre (P_r/P_c GEMM) blocks ------
__global__ __launch_bounds__(512) void mid_kernel(
    const int* __restrict__ ei,
    int* __restrict__ csr_pos, int* __restrict__ bucket,
    const float* __restrict__ h, const __bf16* __restrict__ pw1,
    __bf16* __restrict__ pr, __bf16* __restrict__ pc)
{
    __shared__ __align__(16) __bf16 hs[128 * MS];
    const int t = threadIdx.x;

    if (blockIdx.x < NBUCKET) {
        int i = blockIdx.x * 512 + t;
        if (i < NE_) {
            int p = atomicAdd(&csr_pos[ei[i]], 1);
            bucket[p] = i;
        }
        return;
    }

    const int bp = blockIdx.x - NBUCKET;      // 0..79
    const int b = bp / 40;
    const int n0 = (bp % 40) * 128;
    const int lane = t & 63, wave = t >> 6;   // wave = nt (8 feat-tiles)
    const int quad = lane >> 4, c = lane & 15;

    #pragma unroll
    for (int it = 0; it < 8; it++) {
        int idx = it * 512 + t;               // 0..4095
        int node = idx >> 5, ch = idx & 31;
        int gn = n0 + node;
        float4 v = (gn < NN_) ? *(const float4*)&h[((size_t)b * NN_ + gn) * F + ch * 4]
                              : (float4){0.f, 0.f, 0.f, 0.f};
        bf16x4 bv = {(__bf16)v.x, (__bf16)v.y, (__bf16)v.z, (__bf16)v.w};
        *(bf16x4*)&hs[node * MS + ch * 4] = bv;
    }
    __syncthreads();

    const bf16x8* pw1v = (const bf16x8*)pw1;
    f32x4 accr[8], accc[8];
    #pragma unroll
    for (int m = 0; m < 8; m++) { accr[m] = (f32x4){0,0,0,0}; accc[m] = (f32x4){0,0,0,0}; }
    for (int kt = 0; kt < 4; kt++) {
        bf16x8 wr = pw1v[(wave * 9 + kt) * 64 + lane];       // We1 rows 0..127
        bf16x8 wc = pw1v[(wave * 9 + kt + 4) * 64 + lane];   // We1 rows 128..255
        #pragma unroll
        for (int m = 0; m < 8; m++) {
            bf16x8 x = *(const bf16x8*)&hs[(m * 16 + c) * MS + kt * 32 + quad * 8];
            accr[m] = __builtin_amdgcn_mfma_f32_16x16x32_bf16(wr, x, accr[m], 0, 0, 0);
            accc[m] = __builtin_amdgcn_mfma_f32_16x16x32_bf16(wc, x, accc[m], 0, 0, 0);
        }
    }
    #pragma unroll
    for (int m = 0; m < 8; m++) {
        int gn = n0 + m * 16 + c;
        if (gn < NN_) {
            size_t base = ((size_t)b * NN_ + gn) * F + wave * 16 + quad * 4;
            bf16x4 orr = {(__bf16)accr[m][0], (__bf16)accr[m][1], (__bf16)accr[m][2], (__bf16)accr[m][3]};
            bf16x4 occ = {(__bf16)accc[m][0], (__bf16)accc[m][1], (__bf16)accc[m][2], (__bf16)accc[m][3]};
            *(bf16x4*)&pr[base] = orr;
            *(bf16x4*)&pc[base] = occ;
        }
    }
}

// ------- edge kernel: staged-presum e1, MFMA chain, R8-geometry seg-reduce -------
// wave owns nt pair {2*wave, 2*wave+1}; m loops all 4 edge m-tiles.
__global__ __launch_bounds__(256, 4) void edge_kernel(
    const __bf16* __restrict__ pr, const __bf16* __restrict__ pc,
    const float* __restrict__ coord,
    const int* __restrict__ ei, const __bf16* __restrict__ eab,
    const int* __restrict__ bucket,
    const float* __restrict__ be1, const float* __restrict__ be2,
    const float* __restrict__ bc1,
    const __bf16* __restrict__ pw1, const __bf16* __restrict__ pw2,
    const __bf16* __restrict__ pwc1, const __bf16* __restrict__ pwc2,
    float* __restrict__ agg_h, float* __restrict__ agg_c)
{
    __shared__ __align__(16) __bf16 buf1[EDG * MS];  // presum -> h1 -> h2
    __shared__ __align__(16) __bf16 buf2[EDG * MS];  // xs32 (stride PS) -> ef
    __shared__ __bf16 cds[EDG][12];
    __shared__ int rs[EDG], cs[EDG];

    const int t = threadIdx.x;            // 0..255
    const int b = blockIdx.y;
    const int p0 = blockIdx.x * EDG;
    const int lane = t & 63, wave = t >> 6;
    const int quad = lane >> 4, c = lane & 15;

    int eid_reg = 0;
    if (t < EDG) {
        eid_reg = bucket[p0 + t];
        rs[t] = ei[eid_reg]; cs[t] = ei[NE_ + eid_reg];
    }
    __syncthreads();

    // ---- stage presum = pr[row] + pc[col] into buf1 (coalesced, all threads) ----
    const __bf16* prb = pr + (size_t)b * NN_ * F;
    const __bf16* pcb = pc + (size_t)b * NN_ * F;
    #pragma unroll
    for (int it = 0; it < 4; it++) {
        int idx = it * 256 + t;           // 0..1023: 64 edges x 16 chunks of 8
        int e = idx >> 4, ch = idx & 15;
        bf16x8 a = *(const bf16x8*)(prb + (size_t)rs[e] * F + ch * 8);
        bf16x8 v = *(const bf16x8*)(pcb + (size_t)cs[e] * F + ch * 8);
        bf16x8 o;
        #pragma unroll
        for (int j = 0; j < 8; j++) o[j] = (__bf16)((float)a[j] + (float)v[j]);
        *(bf16x8*)&buf1[e * MS + ch * 8] = o;
    }
    // ---- radial + ea (bf16 gather) -> xs32 (buf2 region, stride PS) ----
    if (t < EDG) {
        int e = t;
        const float* cr = coord + ((size_t)b * NN_ + rs[e]) * 12;
        const float* cc = coord + ((size_t)b * NN_ + cs[e]) * 12;
        float cd[12];
        #pragma unroll
        for (int j = 0; j < 12; j++) { cd[j] = cr[j] - cc[j]; cds[e][j] = (__bf16)cd[j]; }
        float prod[16]; float ss = 0.f;
        #pragma unroll
        for (int j = 0; j < 4; j++)
            #pragma unroll
            for (int k = 0; k < 4; k++) {
                float p = cd[j*3]*cd[k*3] + cd[j*3+1]*cd[k*3+1] + cd[j*3+2]*cd[k*3+2];
                prod[j*4 + k] = p; ss += p * p;
            }
        float inv = 1.0f / fmaxf(sqrtf(ss), 1e-12f);
        #pragma unroll
        for (int j = 0; j < 16; j++) buf2[e * PS + j] = (__bf16)(prod[j] * inv);
        const uint4* ep = (const uint4*)(eab + (size_t)eid_reg * ED);
        *(uint4*)&buf2[e * PS + 16] = ep[0];
        *(uint4*)&buf2[e * PS + 24] = ep[1];
    }
    __syncthreads();

    const bf16x8* pw1v  = (const bf16x8*)pw1;
    const bf16x8* pw2v  = (const bf16x8*)pw2;
    const bf16x8* pwc1v = (const bf16x8*)pwc1;
    const bf16x8* pwc2v = (const bf16x8*)pwc2;

    // ---- e1: K=32 (kt=8 of pw1) + presum + bias ----
    f32x4 acc1[4][2];
    #pragma unroll
    for (int m = 0; m < 4; m++)
        #pragma unroll
        for (int n = 0; n < 2; n++) acc1[m][n] = (f32x4){0,0,0,0};
    {
        bf16x8 x1[4];
        #pragma unroll
        for (int m = 0; m < 4; m++)
            x1[m] = *(const bf16x8*)&buf2[(m*16 + c) * PS + quad*8];
        #pragma unroll
        for (int n = 0; n < 2; n++) {
            bf16x8 w = pw1v[((2*wave + n)*9 + 8)*64 + lane];
            #pragma unroll
            for (int m = 0; m < 4; m++)
                acc1[m][n] = __builtin_amdgcn_mfma_f32_16x16x32_bf16(w, x1[m], acc1[m][n], 0, 0, 0);
        }
    }
    #pragma unroll
    for (int n = 0; n < 2; n++) {
        int nt = 2*wave + n;
        float4 bb = *(const float4*)&be1[nt*16 + quad*4];
        #pragma unroll
        for (int m = 0; m < 4; m++) {
            int row = m*16 + c;
            bf16x4 p = *(const bf16x4*)&buf1[row * MS + nt*16 + quad*4];
            bf16x4 o = { (__bf16)fmaxf(acc1[m][n][0] + (float)p[0] + bb.x, 0.f),
                         (__bf16)fmaxf(acc1[m][n][1] + (float)p[1] + bb.y, 0.f),
                         (__bf16)fmaxf(acc1[m][n][2] + (float)p[2] + bb.z, 0.f),
                         (__bf16)fmaxf(acc1[m][n][3] + (float)p[3] + bb.w, 0.f) };
            *(bf16x4*)&buf1[row * MS + nt*16 + quad*4] = o;
        }
    }
    __syncthreads();

    // ---- e2: h1 @ We2 -> ef (buf2, stride MS); epilogue needs no barrier ----
    f32x4 acc2[4][2];
    #pragma unroll
    for (int m = 0; m < 4; m++)
        #pragma unroll
        for (int n = 0; n < 2; n++) acc2[m][n] = (f32x4){0,0,0,0};
    for (int kt = 0; kt < 4; kt++) {
        bf16x8 x[4];
        #pragma unroll
        for (int m = 0; m < 4; m++)
            x[m] = *(const bf16x8*)&buf1[(m*16 + c) * MS + kt*32 + quad*8];
        #pragma unroll
        for (int n = 0; n < 2; n++) {
            bf16x8 w = pw2v[((2*wave + n)*4 + kt)*64 + lane];
            #pragma unroll
            for (int m = 0; m < 4; m++)
                acc2[m][n] = __builtin_amdgcn_mfma_f32_16x16x32_bf16(w, x[m], acc2[m][n], 0, 0, 0);
        }
    }
    #pragma unroll
    for (int n = 0; n < 2; n++) {
        int nt = 2*wave + n;
        float4 bb = *(const float4*)&be2[nt*16 + quad*4];
        #pragma unroll
        for (int m = 0; m < 4; m++) {
            int row = m*16 + c;
            bf16x4 o = { (__bf16)fmaxf(acc2[m][n][0] + bb.x, 0.f),
                         (__bf16)fmaxf(acc2[m][n][1] + bb.y, 0.f),
                         (__bf16)fmaxf(acc2[m][n][2] + bb.z, 0.f),
                         (__bf16)fmaxf(acc2[m][n][3] + bb.w, 0.f) };
            *(bf16x4*)&buf2[row * MS + nt*16 + quad*4] = o;
        }
    }
    __syncthreads();

    // ---- c1: ef @ Wc1 -> buf1 ----
    f32x4 acc3[4][2];
    #pragma unroll
    for (int m = 0; m < 4; m++)
        #pragma unroll
        for (int n = 0; n < 2; n++) acc3[m][n] = (f32x4){0,0,0,0};
    for (int kt = 0; kt < 4; kt++) {
        bf16x8 x[4];
        #pragma unroll
        for (int m = 0; m < 4; m++)
            x[m] = *(const bf16x8*)&buf2[(m*16 + c) * MS + kt*32 + quad*8];
        #pragma unroll
        for (int n = 0; n < 2; n++) {
            bf16x8 w = pwc1v[((2*wave + n)*4 + kt)*64 + lane];
            #pragma unroll
            for (int m = 0; m < 4; m++)
                acc3[m][n] = __builtin_amdgcn_mfma_f32_16x16x32_bf16(w, x[m], acc3[m][n], 0, 0, 0);
        }
    }
    #pragma unroll
    for (int n = 0; n < 2; n++) {
        int nt = 2*wave + n;
        float4 bb = *(const float4*)&bc1[nt*16 + quad*4];
        #pragma unroll
        for (int m = 0; m < 4; m++) {
            int row = m*16 + c;
            bf16x4 o = { (__bf16)fmaxf(acc3[m][n][0] + bb.x, 0.f),
                         (__bf16)fmaxf(acc3[m][n][1] + bb.y, 0.f),
                         (__bf16)fmaxf(acc3[m][n][2] + bb.z, 0.f),
                         (__bf16)fmaxf(acc3[m][n][3] + bb.w, 0.f) };
            *(bf16x4*)&buf1[row * MS + nt*16 + quad*4] = o;
        }
    }
    __syncthreads();

    // ---- c2: wave owns m-tile = wave (edges wave*16..+15) ----
    f32x4 accw = (f32x4){0,0,0,0};
    for (int kt = 0; kt < 4; kt++) {
        bf16x8 x = *(const bf16x8*)&buf1[(wave*16 + c) * MS + kt*32 + quad*8];
        accw = __builtin_amdgcn_mfma_f32_16x16x32_bf16(pwc2v[kt*64 + lane], x, accw, 0, 0, 0);
    }
    if (quad == 0) {
        int e = wave*16 + c;
        #pragma unroll
        for (int j = 0; j < 12; j++)
            cds[e][j] = (__bf16)((float)cds[e][j] * accw[j/3]);
    }
    __syncthreads();

    // ---- segmented reduction (R8 geometry: scalar u16, 128 cols x 2 segs of 32) ----
    {
        float* aggh_b = agg_h + (size_t)b * NN_ * HID;
        const int col = t & 127, seg = t >> 7;    // 2 segs x 32 edges
        float run = 0.f;
        int cur = rs[seg * 32];
        for (int e = seg * 32; e < seg * 32 + 32; e++) {
            int r = rs[e];
            float v = (float)buf2[e * MS + col];
            if (r != cur) {
                atomicAdd(&aggh_b[(size_t)cur * HID + col], run);
                run = 0.f; cur = r;
            }
            run += v;
        }
        atomicAdd(&aggh_b[(size_t)cur * HID + col], run);
    }
    if (t < 24) {
        float* aggc_b = agg_c + (size_t)b * NN_ * 12;
        const int j = t % 12, q = t / 12;         // 2 segs x 32 edges
        float run = 0.f;
        int cur = rs[q * 32];
        for (int e = q * 32; e < q * 32 + 32; e++) {
            int r = rs[e];
            float v = (float)cds[e][j];
            if (r != cur) {
                atomicAdd(&aggc_b[(size_t)cur * 12 + j], run);
                run = 0.f; cur = r;
            }
            run += v;
        }
        atomicAdd(&aggc_b[(size_t)cur * 12 + j], run);
    }
}

// ------- node kernel: MFMA bf16 MLP + residual + fused coord update -------
__global__ __launch_bounds__(256) void node_kernel(
    const float* __restrict__ h, const float* __restrict__ agg_h,
    const float* __restrict__ agg_c, const float* __restrict__ coord,
    const int* __restrict__ csr_off,
    const __bf16* __restrict__ pwn1, const float* __restrict__ bn1,
    const __bf16* __restrict__ pwn2, const float* __restrict__ bn2,
    float* __restrict__ out_h, float* __restrict__ out_c)
{
    __shared__ __align__(16) __bf16 zs[NPB2 * ZS];   // reused as os (fp32, stride 132)
    __shared__ __align__(16) __bf16 h1s[NPB2 * HS];
    const int t = threadIdx.x;
    const int b = blockIdx.y;
    const int n0 = blockIdx.x * NPB2;
    const int lane = t & 63, wave = t >> 6;
    const int quad = lane >> 4, c = lane & 15;

    #pragma unroll
    for (int it = 0; it < 8; it++) {
        int idx = it * 256 + t;              // 0..2047
        int node = idx >> 6, ch = idx & 63;  // ch 0..31 = h, 32..63 = agg_h
        int gn = n0 + node;
        float4 v = (float4){0.f, 0.f, 0.f, 0.f};
        if (gn < NN_) {
            const float* src = (ch < 32) ? &h[((size_t)b * NN_ + gn) * F + ch * 4]
                                         : &agg_h[((size_t)b * NN_ + gn) * HID + (ch - 32) * 4];
            v = *(const float4*)src;
        }
        bf16x4 bv = {(__bf16)v.x, (__bf16)v.y, (__bf16)v.z, (__bf16)v.w};
        *(bf16x4*)&zs[node * ZS + ch * 4] = bv;
    }
    __syncthreads();

    const bf16x8* w1v = (const bf16x8*)pwn1;
    const bf16x8* w2v = (const bf16x8*)pwn2;
    f32x4 a1[2][2];
    #pragma unroll
    for (int m = 0; m < 2; m++)
        #pragma unroll
        for (int n = 0; n < 2; n++) a1[m][n] = (f32x4){0,0,0,0};
    for (int kt = 0; kt < 8; kt++) {
        bf16x8 x[2];
        #pragma unroll
        for (int m = 0; m < 2; m++)
            x[m] = *(const bf16x8*)&zs[(m*16 + c) * ZS + kt*32 + quad*8];
        #pragma unroll
        for (int n = 0; n < 2; n++) {
            bf16x8 w = w1v[((2*wave + n)*8 + kt)*64 + lane];
            #pragma unroll
            for (int m = 0; m < 2; m++)
                a1[m][n] = __builtin_amdgcn_mfma_f32_16x16x32_bf16(w, x[m], a1[m][n], 0, 0, 0);
        }
    }
    __syncthreads();
    #pragma unroll
    for (int n = 0; n < 2; n++) {
        int nt = 2*wave + n;
        float4 bb = *(const float4*)&bn1[nt*16 + quad*4];
        #pragma unroll
        for (int m = 0; m < 2; m++) {
            bf16x4 o = { (__bf16)fmaxf(a1[m][n][0] + bb.x, 0.f),
                         (__bf16)fmaxf(a1[m][n][1] + bb.y, 0.f),
                         (__bf16)fmaxf(a1[m][n][2] + bb.z, 0.f),
                         (__bf16)fmaxf(a1[m][n][3] + bb.w, 0.f) };
            *(bf16x4*)&h1s[(m*16 + c) * HS + nt*16 + quad*4] = o;
        }
    }
    __syncthreads();

    f32x4 a2[2][2];
    #pragma unroll
    for (int m = 0; m < 2; m++)
        #pragma unroll
        for (int n = 0; n < 2; n++) a2[m][n] = (f32x4){0,0,0,0};
    for (int kt = 0; kt < 4; kt++) {
        bf16x8 x[2];
        #pragma unroll
        for (int m = 0; m < 2; m++)
            x[m] = *(const bf16x8*)&h1s[(m*16 + c) * HS + kt*32 + quad*8];
        #pragma unroll
        for (int n = 0; n < 2; n++) {
            bf16x8 w = w2v[((2*wave + n)*4 + kt)*64 + lane];
            #pragma unroll
            for (int m = 0; m < 2; m++)
                a2[m][n] = __builtin_amdgcn_mfma_f32_16x16x32_bf16(w, x[m], a2[m][n], 0, 0, 0);
        }
    }
    float* os = (float*)zs;   // stride 132 floats
    #pragma unroll
    for (int n = 0; n < 2; n++) {
        int nt = 2*wave + n;
        float4 bb = *(const float4*)&bn2[nt*16 + quad*4];
        #pragma unroll
        for (int m = 0; m < 2; m++) {
            f32x4 o = { a2[m][n][0] + bb.x, a2[m][n][1] + bb.y,
                        a2[m][n][2] + bb.z, a2[m][n][3] + bb.w };
            *(f32x4*)&os[(m*16 + c) * 132 + nt*16 + quad*4] = o;
        }
    }
    __syncthreads();

    #pragma unroll
    for (int it = 0; it < 4; it++) {
        int idx = it * 256 + t;              // 0..1023
        int node = idx >> 5, ch = idx & 31;
        int gn = n0 + node;
        if (gn < NN_) {
            size_t gb = ((size_t)b * NN_ + gn) * F + ch * 4;
            float4 hres = *(const float4*)&h[gb];
            float4 acc = *(const float4*)&os[node * 132 + ch * 4];
            float4 o = { hres.x + acc.x, hres.y + acc.y, hres.z + acc.z, hres.w + acc.w };
            *(float4*)&out_h[gb] = o;
        }
    }
    for (int idx = t; idx < NPB2 * 12; idx += 256) {
        int node = idx / 12, j = idx % 12;
        int gn = n0 + node;
        if (gn < NN_) {
            float deg = (float)(csr_off[gn + 1] - csr_off[gn]);
            size_t ci = ((size_t)b * NN_ + gn) * 12 + j;
            out_c[ci] = coord[ci] + agg_c[ci] / fmaxf(deg, 1.0f);
        }
    }
}

extern "C" void kernel_launch(void* const* d_in, const int* in_sizes, int n_in,
                              void* d_out, int out_size, void* d_ws, size_t ws_size,
                              hipStream_t stream) {
    const float* h     = (const float*)d_in[0];
    const float* coord = (const float*)d_in[1];
    const int*   ei    = (const int*)d_in[2];
    const float* ea    = (const float*)d_in[3];
    const float* We1   = (const float*)d_in[4];
    const float* be1   = (const float*)d_in[5];
    const float* We2   = (const float*)d_in[6];
    const float* be2   = (const float*)d_in[7];
    const float* Wn1   = (const float*)d_in[8];
    const float* bn1   = (const float*)d_in[9];
    const float* Wn2   = (const float*)d_in[10];
    const float* bn2   = (const float*)d_in[11];
    const float* Wc1   = (const float*)d_in[12];
    const float* bc1   = (const float*)d_in[13];
    const float* Wc2   = (const float*)d_in[14];

    float* out_h = (float*)d_out;                       // [B,N,F]
    float* out_c = out_h + (size_t)B * NN_ * F;         // [B,N,4,3]

    unsigned char* base = (unsigned char*)d_ws;
    __bf16* pw1  = (__bf16*)base;             // 36864 bf16
    __bf16* pw2  = pw1 + 36864;               // 16384
    __bf16* pwc1 = pw2 + 16384;               // 16384
    __bf16* pwc2 = pwc1 + 16384;              // 2048
    __bf16* pwn1 = pwc2 + 2048;               // 32768
    __bf16* pwn2 = pwn1 + 32768;              // 16384  -> 120832 elems = 241664 B
    unsigned char* dyn = base + 241664;

    int* csr_cnt = (int*)(dyn);               // 20000 B
    int* csr_off = (int*)(dyn + 20000);       // 20016 B
    int* csr_pos = (int*)(dyn + 40016);       // 20000 B
    int* bucket  = (int*)(dyn + 60016);       // 640000 B
    float* agg_h = (float*)(dyn + 700016);    // [B,N,HID]  5,120,000 B
    float* agg_c = agg_h + (size_t)B * NN_ * HID;      // [B,N,12] 480,000 B
    __bf16* pr   = (__bf16*)(agg_c + (size_t)B * NN_ * 12);  // 2,560,000 B
    __bf16* pc   = pr + (size_t)B * NN_ * F;                 // 2,560,000 B
    __bf16* eab  = pc + (size_t)B * NN_ * F;                 // 5,120,000 B

    pack_weights<<<472, 256, 0, stream>>>(We1, We2, Wc1, Wc2, Wn1, Wn2,
                                          pw1, pw2, pwc1, pwc2, pwn1, pwn2,
                                          (float4*)agg_h, csr_cnt);

    hist_kernel<<<625, 256, 0, stream>>>(ei, ea, csr_cnt, eab);
    scan_kernel<<<1, 512, 0, stream>>>(csr_cnt, csr_off, csr_pos);

    mid_kernel<<<NBUCKET + 80, 512, 0, stream>>>(ei, csr_pos, bucket, h, pw1, pr, pc);

    dim3 eg(NE_ / EDG, B);   // 2500 x 2
    edge_kernel<<<eg, 256, 0, stream>>>(pr, pc, coord, ei, eab, bucket, be1, be2, bc1,
                                        pw1, pw2, pwc1, pwc2, agg_h, agg_c);

    dim3 ng((NN_ + NPB2 - 1) / NPB2, B);   // 157 x 2
    node_kernel<<<ng, 256, 0, stream>>>(h, agg_h, agg_c, coord, csr_off,
                                        pwn1, bn1, pwn2, bn2, out_h, out_c);
}

// Round 17
// 195.618 us; speedup vs baseline: 1.5337x; 1.0228x over previous
//
#include <hip/hip_runtime.h>
#include <hip/hip_bf16.h>

#define B   2
#define NN_ 5000
#define NE_ 160000
#define F   128
#define HID 128
#define ED  16

typedef __bf16 bf16x8 __attribute__((ext_vector_type(8)));
typedef __bf16 bf16x4 __attribute__((ext_vector_type(4)));
typedef float  f32x4  __attribute__((ext_vector_type(4)));

#define MS  136   // edge buf row stride (17 16B-units, odd -> conflict-free b128)
#define PS  40    // xs32 row stride
#define EDG 64    // edges per block
#define ZS  264   // node z row stride bf16
#define HS  136   // node h1 row stride
#define NPB2 32   // nodes per block
#define NBUCKET 313  // bucket blocks in mid_kernel (313*512 >= NE_)

// ------ pack weights + zero agg (blocks 0..471) | histogram (blocks 472..1096) ------
// csr_cnt is zeroed by a preceding hipMemsetAsync (stream-ordered).
// frag: lane l holds W[k = kt*32 + (l>>4)*8 + j][n = nt*16 + (l&15)]; used as
// A-operand (W^T): D = W^T x X^T -> D[feat][edge] (col=edge, row=quad*4+i).
__global__ void pack_hist_kernel(const float* __restrict__ We1, const float* __restrict__ We2,
                                 const float* __restrict__ Wc1, const float* __restrict__ Wc2,
                                 const float* __restrict__ Wn1, const float* __restrict__ Wn2,
                                 const int* __restrict__ ei,
                                 __bf16* __restrict__ pw1, __bf16* __restrict__ pw2,
                                 __bf16* __restrict__ pwc1, __bf16* __restrict__ pwc2,
                                 __bf16* __restrict__ pwn1, __bf16* __restrict__ pwn2,
                                 float4* __restrict__ agg4, int* __restrict__ csr_cnt)
{
    if (blockIdx.x >= 472) {
        // histogram part
        int i = (blockIdx.x - 472) * 256 + threadIdx.x;
        if (i < NE_) atomicAdd(&csr_cnt[ei[i]], 1);
        return;
    }
    int idx = blockIdx.x * 256 + threadIdx.x;   // 0 .. 120831
    const float* W; __bf16* P; int KT, Nr, local;
    if (idx < 36864)       { W = We1; P = pw1;  KT = 9; Nr = 128; local = idx; }
    else if (idx < 53248)  { W = We2; P = pw2;  KT = 4; Nr = 128; local = idx - 36864; }
    else if (idx < 69632)  { W = Wc1; P = pwc1; KT = 4; Nr = 128; local = idx - 53248; }
    else if (idx < 71680)  { W = Wc2; P = pwc2; KT = 4; Nr = 4;   local = idx - 69632; }
    else if (idx < 104448) { W = Wn1; P = pwn1; KT = 8; Nr = 128; local = idx - 71680; }
    else                   { W = Wn2; P = pwn2; KT = 4; Nr = 128; local = idx - 104448; }
    int j = local & 7, lane = (local >> 3) & 63, rest = local >> 9;
    int kt = rest % KT, nt = rest / KT;
    int k = kt * 32 + (lane >> 4) * 8 + j;
    int n = nt * 16 + (lane & 15);
    float v = (n < Nr) ? W[k * Nr + n] : 0.f;
    P[local] = (__bf16)v;

    // zero agg_h+agg_c (contiguous, 350000 float4)
    float4 z4 = {0.f, 0.f, 0.f, 0.f};
    for (int i = idx; i < 350000; i += 120832) agg4[i] = z4;
}

__global__ __launch_bounds__(512) void scan_kernel(const int* __restrict__ csr_cnt,
                                                   int* __restrict__ csr_off, int* __restrict__ csr_pos)
{
    __shared__ int part[512];
    const int t = threadIdx.x;
    int sum = 0;
    #pragma unroll
    for (int j = 0; j < 10; j++) {
        int idx = t * 10 + j;
        if (idx < NN_) sum += csr_cnt[idx];
    }
    part[t] = sum;
    __syncthreads();
    for (int off = 1; off < 512; off <<= 1) {
        int v = (t >= off) ? part[t - off] : 0;
        __syncthreads();
        part[t] += v;
        __syncthreads();
    }
    int run = part[t] - sum;   // exclusive base of this thread's chunk
    #pragma unroll
    for (int j = 0; j < 10; j++) {
        int idx = t * 10 + j;
        if (idx < NN_) { csr_off[idx] = run; csr_pos[idx] = run; run += csr_cnt[idx]; }
    }
    if (t == 0) csr_off[NN_] = NE_;
}

// ------ mid kernel: bucket blocks || pre (P_r/P_c GEMM) blocks ------
__global__ __launch_bounds__(512) void mid_kernel(
    const int* __restrict__ ei,
    int* __restrict__ csr_pos, int* __restrict__ bucket,
    const float* __restrict__ h, const __bf16* __restrict__ pw1,
    __bf16* __restrict__ pr, __bf16* __restrict__ pc)
{
    __shared__ __align__(16) __bf16 hs[128 * MS];
    const int t = threadIdx.x;

    if (blockIdx.x < NBUCKET) {
        int i = blockIdx.x * 512 + t;
        if (i < NE_) {
            int p = atomicAdd(&csr_pos[ei[i]], 1);
            bucket[p] = i;
        }
        return;
    }

    const int bp = blockIdx.x - NBUCKET;      // 0..79
    const int b = bp / 40;
    const int n0 = (bp % 40) * 128;
    const int lane = t & 63, wave = t >> 6;   // wave = nt (8 feat-tiles)
    const int quad = lane >> 4, c = lane & 15;

    #pragma unroll
    for (int it = 0; it < 8; it++) {
        int idx = it * 512 + t;               // 0..4095
        int node = idx >> 5, ch = idx & 31;
        int gn = n0 + node;
        float4 v = (gn < NN_) ? *(const float4*)&h[((size_t)b * NN_ + gn) * F + ch * 4]
                              : (float4){0.f, 0.f, 0.f, 0.f};
        bf16x4 bv = {(__bf16)v.x, (__bf16)v.y, (__bf16)v.z, (__bf16)v.w};
        *(bf16x4*)&hs[node * MS + ch * 4] = bv;
    }
    __syncthreads();

    const bf16x8* pw1v = (const bf16x8*)pw1;
    f32x4 accr[8], accc[8];
    #pragma unroll
    for (int m = 0; m < 8; m++) { accr[m] = (f32x4){0,0,0,0}; accc[m] = (f32x4){0,0,0,0}; }
    for (int kt = 0; kt < 4; kt++) {
        bf16x8 wr = pw1v[(wave * 9 + kt) * 64 + lane];       // We1 rows 0..127
        bf16x8 wc = pw1v[(wave * 9 + kt + 4) * 64 + lane];   // We1 rows 128..255
        #pragma unroll
        for (int m = 0; m < 8; m++) {
            bf16x8 x = *(const bf16x8*)&hs[(m * 16 + c) * MS + kt * 32 + quad * 8];
            accr[m] = __builtin_amdgcn_mfma_f32_16x16x32_bf16(wr, x, accr[m], 0, 0, 0);
            accc[m] = __builtin_amdgcn_mfma_f32_16x16x32_bf16(wc, x, accc[m], 0, 0, 0);
        }
    }
    #pragma unroll
    for (int m = 0; m < 8; m++) {
        int gn = n0 + m * 16 + c;
        if (gn < NN_) {
            size_t base = ((size_t)b * NN_ + gn) * F + wave * 16 + quad * 4;
            bf16x4 orr = {(__bf16)accr[m][0], (__bf16)accr[m][1], (__bf16)accr[m][2], (__bf16)accr[m][3]};
            bf16x4 occ = {(__bf16)accc[m][0], (__bf16)accc[m][1], (__bf16)accc[m][2], (__bf16)accc[m][3]};
            *(bf16x4*)&pr[base] = orr;
            *(bf16x4*)&pc[base] = occ;
        }
    }
}

// ------- edge kernel: staged-presum e1, MFMA chain, R8-geometry seg-reduce -------
// wave owns nt pair {2*wave, 2*wave+1}; m loops all 4 edge m-tiles.
__global__ __launch_bounds__(256, 4) void edge_kernel(
    const __bf16* __restrict__ pr, const __bf16* __restrict__ pc,
    const float* __restrict__ coord,
    const int* __restrict__ ei, const float* __restrict__ ea,
    const int* __restrict__ bucket,
    const float* __restrict__ be1, const float* __restrict__ be2,
    const float* __restrict__ bc1,
    const __bf16* __restrict__ pw1, const __bf16* __restrict__ pw2,
    const __bf16* __restrict__ pwc1, const __bf16* __restrict__ pwc2,
    float* __restrict__ agg_h, float* __restrict__ agg_c)
{
    __shared__ __align__(16) __bf16 buf1[EDG * MS];  // presum -> h1 -> h2
    __shared__ __align__(16) __bf16 buf2[EDG * MS];  // xs32 (stride PS) -> ef
    __shared__ __bf16 cds[EDG][12];
    __shared__ int rs[EDG], cs[EDG];

    const int t = threadIdx.x;            // 0..255
    const int b = blockIdx.y;
    const int p0 = blockIdx.x * EDG;
    const int lane = t & 63, wave = t >> 6;
    const int quad = lane >> 4, c = lane & 15;

    int eid_reg = 0;
    if (t < EDG) {
        eid_reg = bucket[p0 + t];
        rs[t] = ei[eid_reg]; cs[t] = ei[NE_ + eid_reg];
    }
    __syncthreads();

    // ---- stage presum = pr[row] + pc[col] into buf1 (coalesced, all threads) ----
    const __bf16* prb = pr + (size_t)b * NN_ * F;
    const __bf16* pcb = pc + (size_t)b * NN_ * F;
    #pragma unroll
    for (int it = 0; it < 4; it++) {
        int idx = it * 256 + t;           // 0..1023: 64 edges x 16 chunks of 8
        int e = idx >> 4, ch = idx & 15;
        bf16x8 a = *(const bf16x8*)(prb + (size_t)rs[e] * F + ch * 8);
        bf16x8 v = *(const bf16x8*)(pcb + (size_t)cs[e] * F + ch * 8);
        bf16x8 o;
        #pragma unroll
        for (int j = 0; j < 8; j++) o[j] = (__bf16)((float)a[j] + (float)v[j]);
        *(bf16x8*)&buf1[e * MS + ch * 8] = o;
    }
    // ---- radial + ea (direct fp32 gather) -> xs32 (buf2 region, stride PS) ----
    if (t < EDG) {
        int e = t;
        const float* cr = coord + ((size_t)b * NN_ + rs[e]) * 12;
        const float* cc = coord + ((size_t)b * NN_ + cs[e]) * 12;
        float cd[12];
        #pragma unroll
        for (int j = 0; j < 12; j++) { cd[j] = cr[j] - cc[j]; cds[e][j] = (__bf16)cd[j]; }
        float prod[16]; float ss = 0.f;
        #pragma unroll
        for (int j = 0; j < 4; j++)
            #pragma unroll
            for (int k = 0; k < 4; k++) {
                float p = cd[j*3]*cd[k*3] + cd[j*3+1]*cd[k*3+1] + cd[j*3+2]*cd[k*3+2];
                prod[j*4 + k] = p; ss += p * p;
            }
        float inv = 1.0f / fmaxf(sqrtf(ss), 1e-12f);
        #pragma unroll
        for (int j = 0; j < 16; j++) buf2[e * PS + j] = (__bf16)(prod[j] * inv);
        const float4* ep = (const float4*)(ea + (size_t)eid_reg * ED);
        #pragma unroll
        for (int j = 0; j < 4; j++) {
            float4 v = ep[j];
            bf16x4 bv = {(__bf16)v.x, (__bf16)v.y, (__bf16)v.z, (__bf16)v.w};
            *(bf16x4*)&buf2[e * PS + 16 + j * 4] = bv;
        }
    }
    __syncthreads();

    const bf16x8* pw1v  = (const bf16x8*)pw1;
    const bf16x8* pw2v  = (const bf16x8*)pw2;
    const bf16x8* pwc1v = (const bf16x8*)pwc1;
    const bf16x8* pwc2v = (const bf16x8*)pwc2;

    // ---- e1: K=32 (kt=8 of pw1) + presum + bias ----
    f32x4 acc1[4][2];
    #pragma unroll
    for (int m = 0; m < 4; m++)
        #pragma unroll
        for (int n = 0; n < 2; n++) acc1[m][n] = (f32x4){0,0,0,0};
    {
        bf16x8 x1[4];
        #pragma unroll
        for (int m = 0; m < 4; m++)
            x1[m] = *(const bf16x8*)&buf2[(m*16 + c) * PS + quad*8];
        #pragma unroll
        for (int n = 0; n < 2; n++) {
            bf16x8 w = pw1v[((2*wave + n)*9 + 8)*64 + lane];
            #pragma unroll
            for (int m = 0; m < 4; m++)
                acc1[m][n] = __builtin_amdgcn_mfma_f32_16x16x32_bf16(w, x1[m], acc1[m][n], 0, 0, 0);
        }
    }
    #pragma unroll
    for (int n = 0; n < 2; n++) {
        int nt = 2*wave + n;
        float4 bb = *(const float4*)&be1[nt*16 + quad*4];
        #pragma unroll
        for (int m = 0; m < 4; m++) {
            int row = m*16 + c;
            bf16x4 p = *(const bf16x4*)&buf1[row * MS + nt*16 + quad*4];
            bf16x4 o = { (__bf16)fmaxf(acc1[m][n][0] + (float)p[0] + bb.x, 0.f),
                         (__bf16)fmaxf(acc1[m][n][1] + (float)p[1] + bb.y, 0.f),
                         (__bf16)fmaxf(acc1[m][n][2] + (float)p[2] + bb.z, 0.f),
                         (__bf16)fmaxf(acc1[m][n][3] + (float)p[3] + bb.w, 0.f) };
            *(bf16x4*)&buf1[row * MS + nt*16 + quad*4] = o;
        }
    }
    __syncthreads();

    // ---- e2: h1 @ We2 -> ef (buf2, stride MS); epilogue needs no barrier ----
    f32x4 acc2[4][2];
    #pragma unroll
    for (int m = 0; m < 4; m++)
        #pragma unroll
        for (int n = 0; n < 2; n++) acc2[m][n] = (f32x4){0,0,0,0};
    for (int kt = 0; kt < 4; kt++) {
        bf16x8 x[4];
        #pragma unroll
        for (int m = 0; m < 4; m++)
            x[m] = *(const bf16x8*)&buf1[(m*16 + c) * MS + kt*32 + quad*8];
        #pragma unroll
        for (int n = 0; n < 2; n++) {
            bf16x8 w = pw2v[((2*wave + n)*4 + kt)*64 + lane];
            #pragma unroll
            for (int m = 0; m < 4; m++)
                acc2[m][n] = __builtin_amdgcn_mfma_f32_16x16x32_bf16(w, x[m], acc2[m][n], 0, 0, 0);
        }
    }
    #pragma unroll
    for (int n = 0; n < 2; n++) {
        int nt = 2*wave + n;
        float4 bb = *(const float4*)&be2[nt*16 + quad*4];
        #pragma unroll
        for (int m = 0; m < 4; m++) {
            int row = m*16 + c;
            bf16x4 o = { (__bf16)fmaxf(acc2[m][n][0] + bb.x, 0.f),
                         (__bf16)fmaxf(acc2[m][n][1] + bb.y, 0.f),
                         (__bf16)fmaxf(acc2[m][n][2] + bb.z, 0.f),
                         (__bf16)fmaxf(acc2[m][n][3] + bb.w, 0.f) };
            *(bf16x4*)&buf2[row * MS + nt*16 + quad*4] = o;
        }
    }
    __syncthreads();

    // ---- c1: ef @ Wc1 -> buf1 ----
    f32x4 acc3[4][2];
    #pragma unroll
    for (int m = 0; m < 4; m++)
        #pragma unroll
        for (int n = 0; n < 2; n++) acc3[m][n] = (f32x4){0,0,0,0};
    for (int kt = 0; kt < 4; kt++) {
        bf16x8 x[4];
        #pragma unroll
        for (int m = 0; m < 4; m++)
            x[m] = *(const bf16x8*)&buf2[(m*16 + c) * MS + kt*32 + quad*8];
        #pragma unroll
        for (int n = 0; n < 2; n++) {
            bf16x8 w = pwc1v[((2*wave + n)*4 + kt)*64 + lane];
            #pragma unroll
            for (int m = 0; m < 4; m++)
                acc3[m][n] = __builtin_amdgcn_mfma_f32_16x16x32_bf16(w, x[m], acc3[m][n], 0, 0, 0);
        }
    }
    #pragma unroll
    for (int n = 0; n < 2; n++) {
        int nt = 2*wave + n;
        float4 bb = *(const float4*)&bc1[nt*16 + quad*4];
        #pragma unroll
        for (int m = 0; m < 4; m++) {
            int row = m*16 + c;
            bf16x4 o = { (__bf16)fmaxf(acc3[m][n][0] + bb.x, 0.f),
                         (__bf16)fmaxf(acc3[m][n][1] + bb.y, 0.f),
                         (__bf16)fmaxf(acc3[m][n][2] + bb.z, 0.f),
                         (__bf16)fmaxf(acc3[m][n][3] + bb.w, 0.f) };
            *(bf16x4*)&buf1[row * MS + nt*16 + quad*4] = o;
        }
    }
    __syncthreads();

    // ---- c2: wave owns m-tile = wave (edges wave*16..+15) ----
    f32x4 accw = (f32x4){0,0,0,0};
    for (int kt = 0; kt < 4; kt++) {
        bf16x8 x = *(const bf16x8*)&buf1[(wave*16 + c) * MS + kt*32 + quad*8];
        accw = __builtin_amdgcn_mfma_f32_16x16x32_bf16(pwc2v[kt*64 + lane], x, accw, 0, 0, 0);
    }
    if (quad == 0) {
        int e = wave*16 + c;
        #pragma unroll
        for (int j = 0; j < 12; j++)
            cds[e][j] = (__bf16)((float)cds[e][j] * accw[j/3]);
    }
    __syncthreads();

    // ---- segmented reduction (R8 geometry: scalar u16, 128 cols x 2 segs of 32) ----
    {
        float* aggh_b = agg_h + (size_t)b * NN_ * HID;
        const int col = t & 127, seg = t >> 7;    // 2 segs x 32 edges
        float run = 0.f;
        int cur = rs[seg * 32];
        for (int e = seg * 32; e < seg * 32 + 32; e++) {
            int r = rs[e];
            float v = (float)buf2[e * MS + col];
            if (r != cur) {
                atomicAdd(&aggh_b[(size_t)cur * HID + col], run);
                run = 0.f; cur = r;
            }
            run += v;
        }
        atomicAdd(&aggh_b[(size_t)cur * HID + col], run);
    }
    if (t < 24) {
        float* aggc_b = agg_c + (size_t)b * NN_ * 12;
        const int j = t % 12, q = t / 12;         // 2 segs x 32 edges
        float run = 0.f;
        int cur = rs[q * 32];
        for (int e = q * 32; e < q * 32 + 32; e++) {
            int r = rs[e];
            float v = (float)cds[e][j];
            if (r != cur) {
                atomicAdd(&aggc_b[(size_t)cur * 12 + j], run);
                run = 0.f; cur = r;
            }
            run += v;
        }
        atomicAdd(&aggc_b[(size_t)cur * 12 + j], run);
    }
}

// ------- node kernel: MFMA bf16 MLP + residual + fused coord update -------
__global__ __launch_bounds__(256) void node_kernel(
    const float* __restrict__ h, const float* __restrict__ agg_h,
    const float* __restrict__ agg_c, const float* __restrict__ coord,
    const int* __restrict__ csr_off,
    const __bf16* __restrict__ pwn1, const float* __restrict__ bn1,
    const __bf16* __restrict__ pwn2, const float* __restrict__ bn2,
    float* __restrict__ out_h, float* __restrict__ out_c)
{
    __shared__ __align__(16) __bf16 zs[NPB2 * ZS];   // reused as os (fp32, stride 132)
    __shared__ __align__(16) __bf16 h1s[NPB2 * HS];
    const int t = threadIdx.x;
    const int b = blockIdx.y;
    const int n0 = blockIdx.x * NPB2;
    const int lane = t & 63, wave = t >> 6;
    const int quad = lane >> 4, c = lane & 15;

    #pragma unroll
    for (int it = 0; it < 8; it++) {
        int idx = it * 256 + t;              // 0..2047
        int node = idx >> 6, ch = idx & 63;  // ch 0..31 = h, 32..63 = agg_h
        int gn = n0 + node;
        float4 v = (float4){0.f, 0.f, 0.f, 0.f};
        if (gn < NN_) {
            const float* src = (ch < 32) ? &h[((size_t)b * NN_ + gn) * F + ch * 4]
                                         : &agg_h[((size_t)b * NN_ + gn) * HID + (ch - 32) * 4];
            v = *(const float4*)src;
        }
        bf16x4 bv = {(__bf16)v.x, (__bf16)v.y, (__bf16)v.z, (__bf16)v.w};
        *(bf16x4*)&zs[node * ZS + ch * 4] = bv;
    }
    __syncthreads();

    const bf16x8* w1v = (const bf16x8*)pwn1;
    const bf16x8* w2v = (const bf16x8*)pwn2;
    f32x4 a1[2][2];
    #pragma unroll
    for (int m = 0; m < 2; m++)
        #pragma unroll
        for (int n = 0; n < 2; n++) a1[m][n] = (f32x4){0,0,0,0};
    for (int kt = 0; kt < 8; kt++) {
        bf16x8 x[2];
        #pragma unroll
        for (int m = 0; m < 2; m++)
            x[m] = *(const bf16x8*)&zs[(m*16 + c) * ZS + kt*32 + quad*8];
        #pragma unroll
        for (int n = 0; n < 2; n++) {
            bf16x8 w = w1v[((2*wave + n)*8 + kt)*64 + lane];
            #pragma unroll
            for (int m = 0; m < 2; m++)
                a1[m][n] = __builtin_amdgcn_mfma_f32_16x16x32_bf16(w, x[m], a1[m][n], 0, 0, 0);
        }
    }
    __syncthreads();
    #pragma unroll
    for (int n = 0; n < 2; n++) {
        int nt = 2*wave + n;
        float4 bb = *(const float4*)&bn1[nt*16 + quad*4];
        #pragma unroll
        for (int m = 0; m < 2; m++) {
            bf16x4 o = { (__bf16)fmaxf(a1[m][n][0] + bb.x, 0.f),
                         (__bf16)fmaxf(a1[m][n][1] + bb.y, 0.f),
                         (__bf16)fmaxf(a1[m][n][2] + bb.z, 0.f),
                         (__bf16)fmaxf(a1[m][n][3] + bb.w, 0.f) };
            *(bf16x4*)&h1s[(m*16 + c) * HS + nt*16 + quad*4] = o;
        }
    }
    __syncthreads();

    f32x4 a2[2][2];
    #pragma unroll
    for (int m = 0; m < 2; m++)
        #pragma unroll
        for (int n = 0; n < 2; n++) a2[m][n] = (f32x4){0,0,0,0};
    for (int kt = 0; kt < 4; kt++) {
        bf16x8 x[2];
        #pragma unroll
        for (int m = 0; m < 2; m++)
            x[m] = *(const bf16x8*)&h1s[(m*16 + c) * HS + kt*32 + quad*8];
        #pragma unroll
        for (int n = 0; n < 2; n++) {
            bf16x8 w = w2v[((2*wave + n)*4 + kt)*64 + lane];
            #pragma unroll
            for (int m = 0; m < 2; m++)
                a2[m][n] = __builtin_amdgcn_mfma_f32_16x16x32_bf16(w, x[m], a2[m][n], 0, 0, 0);
        }
    }
    float* os = (float*)zs;   // stride 132 floats
    #pragma unroll
    for (int n = 0; n < 2; n++) {
        int nt = 2*wave + n;
        float4 bb = *(const float4*)&bn2[nt*16 + quad*4];
        #pragma unroll
        for (int m = 0; m < 2; m++) {
            f32x4 o = { a2[m][n][0] + bb.x, a2[m][n][1] + bb.y,
                        a2[m][n][2] + bb.z, a2[m][n][3] + bb.w };
            *(f32x4*)&os[(m*16 + c) * 132 + nt*16 + quad*4] = o;
        }
    }
    __syncthreads();

    #pragma unroll
    for (int it = 0; it < 4; it++) {
        int idx = it * 256 + t;              // 0..1023
        int node = idx >> 5, ch = idx & 31;
        int gn = n0 + node;
        if (gn < NN_) {
            size_t gb = ((size_t)b * NN_ + gn) * F + ch * 4;
            float4 hres = *(const float4*)&h[gb];
            float4 acc = *(const float4*)&os[node * 132 + ch * 4];
            float4 o = { hres.x + acc.x, hres.y + acc.y, hres.z + acc.z, hres.w + acc.w };
            *(float4*)&out_h[gb] = o;
        }
    }
    for (int idx = t; idx < NPB2 * 12; idx += 256) {
        int node = idx / 12, j = idx % 12;
        int gn = n0 + node;
        if (gn < NN_) {
            float deg = (float)(csr_off[gn + 1] - csr_off[gn]);
            size_t ci = ((size_t)b * NN_ + gn) * 12 + j;
            out_c[ci] = coord[ci] + agg_c[ci] / fmaxf(deg, 1.0f);
        }
    }
}

extern "C" void kernel_launch(void* const* d_in, const int* in_sizes, int n_in,
                              void* d_out, int out_size, void* d_ws, size_t ws_size,
                              hipStream_t stream) {
    const float* h     = (const float*)d_in[0];
    const float* coord = (const float*)d_in[1];
    const int*   ei    = (const int*)d_in[2];
    const float* ea    = (const float*)d_in[3];
    const float* We1   = (const float*)d_in[4];
    const float* be1   = (const float*)d_in[5];
    const float* We2   = (const float*)d_in[6];
    const float* be2   = (const float*)d_in[7];
    const float* Wn1   = (const float*)d_in[8];
    const float* bn1   = (const float*)d_in[9];
    const float* Wn2   = (const float*)d_in[10];
    const float* bn2   = (const float*)d_in[11];
    const float* Wc1   = (const float*)d_in[12];
    const float* bc1   = (const float*)d_in[13];
    const float* Wc2   = (const float*)d_in[14];

    float* out_h = (float*)d_out;                       // [B,N,F]
    float* out_c = out_h + (size_t)B * NN_ * F;         // [B,N,4,3]

    unsigned char* base = (unsigned char*)d_ws;
    __bf16* pw1  = (__bf16*)base;             // 36864 bf16
    __bf16* pw2  = pw1 + 36864;               // 16384
    __bf16* pwc1 = pw2 + 16384;               // 16384
    __bf16* pwc2 = pwc1 + 16384;              // 2048
    __bf16* pwn1 = pwc2 + 2048;               // 32768
    __bf16* pwn2 = pwn1 + 32768;              // 16384  -> 120832 elems = 241664 B
    unsigned char* dyn = base + 241664;

    int* csr_cnt = (int*)(dyn);               // 20000 B
    int* csr_off = (int*)(dyn + 20000);       // 20016 B
    int* csr_pos = (int*)(dyn + 40016);       // 20000 B
    int* bucket  = (int*)(dyn + 60016);       // 640000 B
    float* agg_h = (float*)(dyn + 700016);    // [B,N,HID]  5,120,000 B
    float* agg_c = agg_h + (size_t)B * NN_ * HID;      // [B,N,12] 480,000 B
    __bf16* pr   = (__bf16*)(agg_c + (size_t)B * NN_ * 12);  // 2,560,000 B
    __bf16* pc   = pr + (size_t)B * NN_ * F;                 // 2,560,000 B

    hipMemsetAsync(csr_cnt, 0, 20000, stream);

    pack_hist_kernel<<<472 + 625, 256, 0, stream>>>(We1, We2, Wc1, Wc2, Wn1, Wn2, ei,
                                                    pw1, pw2, pwc1, pwc2, pwn1, pwn2,
                                                    (float4*)agg_h, csr_cnt);

    scan_kernel<<<1, 512, 0, stream>>>(csr_cnt, csr_off, csr_pos);

    mid_kernel<<<NBUCKET + 80, 512, 0, stream>>>(ei, csr_pos, bucket, h, pw1, pr, pc);

    dim3 eg(NE_ / EDG, B);   // 2500 x 2
    edge_kernel<<<eg, 256, 0, stream>>>(pr, pc, coord, ei, ea, bucket, be1, be2, bc1,
                                        pw1, pw2, pwc1, pwc2, agg_h, agg_c);

    dim3 ng((NN_ + NPB2 - 1) / NPB2, B);   // 157 x 2
    node_kernel<<<ng, 256, 0, stream>>>(h, agg_h, agg_c, coord, csr_off,
                                        pwn1, bn1, pwn2, bn2, out_h, out_c);
}

// Round 18
// 194.237 us; speedup vs baseline: 1.5446x; 1.0071x over previous
//
#include <hip/hip_runtime.h>
#include <hip/hip_bf16.h>

#define B   2
#define NN_ 5000
#define NE_ 160000
#define F   128
#define HID 128
#define ED  16

typedef __bf16 bf16x8 __attribute__((ext_vector_type(8)));
typedef __bf16 bf16x4 __attribute__((ext_vector_type(4)));
typedef float  f32x4  __attribute__((ext_vector_type(4)));

#define MS  136   // edge buf row stride (17 16B-units, odd -> conflict-free b128)
#define PS  40    // xs32 row stride
#define EDG 64    // edges per block
#define ZS  264   // node z row stride bf16
#define HS  136   // node h1 row stride
#define NPB2 32   // nodes per block
#define NBUCKET 313  // bucket blocks in mid_kernel (313*512 >= NE_)

// ------ pack weights + zero agg (blocks 0..471) | histogram (blocks 472..1096) ------
// csr_cnt is zeroed by a preceding hipMemsetAsync (stream-ordered).
// frag: lane l holds W[k = kt*32 + (l>>4)*8 + j][n = nt*16 + (l&15)]; used as
// A-operand (W^T): D = W^T x X^T -> D[feat][edge] (col=edge, row=quad*4+i).
__global__ void pack_hist_kernel(const float* __restrict__ We1, const float* __restrict__ We2,
                                 const float* __restrict__ Wc1, const float* __restrict__ Wc2,
                                 const float* __restrict__ Wn1, const float* __restrict__ Wn2,
                                 const int* __restrict__ ei,
                                 __bf16* __restrict__ pw1, __bf16* __restrict__ pw2,
                                 __bf16* __restrict__ pwc1, __bf16* __restrict__ pwc2,
                                 __bf16* __restrict__ pwn1, __bf16* __restrict__ pwn2,
                                 float4* __restrict__ agg4, int* __restrict__ csr_cnt)
{
    if (blockIdx.x >= 472) {
        int i = (blockIdx.x - 472) * 256 + threadIdx.x;
        if (i < NE_) atomicAdd(&csr_cnt[ei[i]], 1);
        return;
    }
    int idx = blockIdx.x * 256 + threadIdx.x;   // 0 .. 120831
    const float* W; __bf16* P; int KT, Nr, local;
    if (idx < 36864)       { W = We1; P = pw1;  KT = 9; Nr = 128; local = idx; }
    else if (idx < 53248)  { W = We2; P = pw2;  KT = 4; Nr = 128; local = idx - 36864; }
    else if (idx < 69632)  { W = Wc1; P = pwc1; KT = 4; Nr = 128; local = idx - 53248; }
    else if (idx < 71680)  { W = Wc2; P = pwc2; KT = 4; Nr = 4;   local = idx - 69632; }
    else if (idx < 104448) { W = Wn1; P = pwn1; KT = 8; Nr = 128; local = idx - 71680; }
    else                   { W = Wn2; P = pwn2; KT = 4; Nr = 128; local = idx - 104448; }
    int j = local & 7, lane = (local >> 3) & 63, rest = local >> 9;
    int kt = rest % KT, nt = rest / KT;
    int k = kt * 32 + (lane >> 4) * 8 + j;
    int n = nt * 16 + (lane & 15);
    float v = (n < Nr) ? W[k * Nr + n] : 0.f;
    P[local] = (__bf16)v;

    // zero agg_h+agg_c (contiguous, 350000 float4)
    float4 z4 = {0.f, 0.f, 0.f, 0.f};
    for (int i = idx; i < 350000; i += 120832) agg4[i] = z4;
}

__global__ __launch_bounds__(512) void scan_kernel(const int* __restrict__ csr_cnt,
                                                   int* __restrict__ csr_off, int* __restrict__ csr_pos)
{
    __shared__ int part[512];
    const int t = threadIdx.x;
    int sum = 0;
    #pragma unroll
    for (int j = 0; j < 10; j++) {
        int idx = t * 10 + j;
        if (idx < NN_) sum += csr_cnt[idx];
    }
    part[t] = sum;
    __syncthreads();
    for (int off = 1; off < 512; off <<= 1) {
        int v = (t >= off) ? part[t - off] : 0;
        __syncthreads();
        part[t] += v;
        __syncthreads();
    }
    int run = part[t] - sum;
    #pragma unroll
    for (int j = 0; j < 10; j++) {
        int idx = t * 10 + j;
        if (idx < NN_) { csr_off[idx] = run; csr_pos[idx] = run; run += csr_cnt[idx]; }
    }
    if (t == 0) csr_off[NN_] = NE_;
}

// ------ mid kernel: bucket blocks || pre (P_r/P_c GEMM) blocks ------
// pre fuses be1 into P_r so the edge kernel's e1 epilogue needs no bias.
__global__ __launch_bounds__(512) void mid_kernel(
    const int* __restrict__ ei,
    int* __restrict__ csr_pos, int* __restrict__ bucket,
    const float* __restrict__ h, const __bf16* __restrict__ pw1,
    const float* __restrict__ be1,
    __bf16* __restrict__ pr, __bf16* __restrict__ pc)
{
    __shared__ __align__(16) __bf16 hs[128 * MS];
    const int t = threadIdx.x;

    if (blockIdx.x < NBUCKET) {
        int i = blockIdx.x * 512 + t;
        if (i < NE_) {
            int p = atomicAdd(&csr_pos[ei[i]], 1);
            bucket[p] = i;
        }
        return;
    }

    const int bp = blockIdx.x - NBUCKET;      // 0..79
    const int b = bp / 40;
    const int n0 = (bp % 40) * 128;
    const int lane = t & 63, wave = t >> 6;   // wave = nt (8 feat-tiles)
    const int quad = lane >> 4, c = lane & 15;

    #pragma unroll
    for (int it = 0; it < 8; it++) {
        int idx = it * 512 + t;               // 0..4095
        int node = idx >> 5, ch = idx & 31;
        int gn = n0 + node;
        float4 v = (gn < NN_) ? *(const float4*)&h[((size_t)b * NN_ + gn) * F + ch * 4]
                              : (float4){0.f, 0.f, 0.f, 0.f};
        bf16x4 bv = {(__bf16)v.x, (__bf16)v.y, (__bf16)v.z, (__bf16)v.w};
        *(bf16x4*)&hs[node * MS + ch * 4] = bv;
    }
    __syncthreads();

    const bf16x8* pw1v = (const bf16x8*)pw1;
    f32x4 accr[8], accc[8];
    #pragma unroll
    for (int m = 0; m < 8; m++) { accr[m] = (f32x4){0,0,0,0}; accc[m] = (f32x4){0,0,0,0}; }
    for (int kt = 0; kt < 4; kt++) {
        bf16x8 wr = pw1v[(wave * 9 + kt) * 64 + lane];       // We1 rows 0..127
        bf16x8 wc = pw1v[(wave * 9 + kt + 4) * 64 + lane];   // We1 rows 128..255
        #pragma unroll
        for (int m = 0; m < 8; m++) {
            bf16x8 x = *(const bf16x8*)&hs[(m * 16 + c) * MS + kt * 32 + quad * 8];
            accr[m] = __builtin_amdgcn_mfma_f32_16x16x32_bf16(wr, x, accr[m], 0, 0, 0);
            accc[m] = __builtin_amdgcn_mfma_f32_16x16x32_bf16(wc, x, accc[m], 0, 0, 0);
        }
    }
    float4 bb = *(const float4*)&be1[wave * 16 + quad * 4];
    #pragma unroll
    for (int m = 0; m < 8; m++) {
        int gn = n0 + m * 16 + c;
        if (gn < NN_) {
            size_t base = ((size_t)b * NN_ + gn) * F + wave * 16 + quad * 4;
            bf16x4 orr = {(__bf16)(accr[m][0] + bb.x), (__bf16)(accr[m][1] + bb.y),
                          (__bf16)(accr[m][2] + bb.z), (__bf16)(accr[m][3] + bb.w)};
            bf16x4 occ = {(__bf16)accc[m][0], (__bf16)accc[m][1], (__bf16)accc[m][2], (__bf16)accc[m][3]};
            *(bf16x4*)&pr[base] = orr;
            *(bf16x4*)&pc[base] = occ;
        }
    }
}

// ------- edge kernel: staged-presum e1, MFMA chain, seg-reduce (agg_h pre-barrier) ----
// wave owns nt pair {2*wave, 2*wave+1}; m loops all 4 edge m-tiles.
__global__ __launch_bounds__(256, 4) void edge_kernel(
    const __bf16* __restrict__ pr, const __bf16* __restrict__ pc,
    const float* __restrict__ coord,
    const int* __restrict__ ei, const float* __restrict__ ea,
    const int* __restrict__ bucket,
    const float* __restrict__ be2, const float* __restrict__ bc1,
    const __bf16* __restrict__ pw1, const __bf16* __restrict__ pw2,
    const __bf16* __restrict__ pwc1, const __bf16* __restrict__ pwc2,
    float* __restrict__ agg_h, float* __restrict__ agg_c)
{
    __shared__ __align__(16) __bf16 buf1[EDG * MS];  // presum -> h1 -> h2
    __shared__ __align__(16) __bf16 buf2[EDG * MS];  // xs32 (stride PS) -> ef
    __shared__ __bf16 cds[EDG][12];
    __shared__ int rs[EDG], cs[EDG];

    const int t = threadIdx.x;            // 0..255
    const int b = blockIdx.y;
    const int p0 = blockIdx.x * EDG;
    const int lane = t & 63, wave = t >> 6;
    const int quad = lane >> 4, c = lane & 15;

    int eid_reg = 0;
    if (t < EDG) {
        eid_reg = bucket[p0 + t];
        rs[t] = ei[eid_reg]; cs[t] = ei[NE_ + eid_reg];
    }
    __syncthreads();

    // ---- stage presum = pr[row](+be1) + pc[col] into buf1 (coalesced) ----
    const __bf16* prb = pr + (size_t)b * NN_ * F;
    const __bf16* pcb = pc + (size_t)b * NN_ * F;
    #pragma unroll
    for (int it = 0; it < 4; it++) {
        int idx = it * 256 + t;           // 0..1023: 64 edges x 16 chunks of 8
        int e = idx >> 4, ch = idx & 15;
        bf16x8 a = *(const bf16x8*)(prb + (size_t)rs[e] * F + ch * 8);
        bf16x8 v = *(const bf16x8*)(pcb + (size_t)cs[e] * F + ch * 8);
        bf16x8 o;
        #pragma unroll
        for (int j = 0; j < 8; j++) o[j] = (__bf16)((float)a[j] + (float)v[j]);
        *(bf16x8*)&buf1[e * MS + ch * 8] = o;
    }
    // ---- radial + ea (direct fp32 gather) -> xs32 (buf2 region, stride PS) ----
    if (t < EDG) {
        int e = t;
        const float* cr = coord + ((size_t)b * NN_ + rs[e]) * 12;
        const float* cc = coord + ((size_t)b * NN_ + cs[e]) * 12;
        float cd[12];
        #pragma unroll
        for (int j = 0; j < 12; j++) { cd[j] = cr[j] - cc[j]; cds[e][j] = (__bf16)cd[j]; }
        float prod[16]; float ss = 0.f;
        #pragma unroll
        for (int j = 0; j < 4; j++)
            #pragma unroll
            for (int k = 0; k < 4; k++) {
                float p = cd[j*3]*cd[k*3] + cd[j*3+1]*cd[k*3+1] + cd[j*3+2]*cd[k*3+2];
                prod[j*4 + k] = p; ss += p * p;
            }
        float inv = 1.0f / fmaxf(sqrtf(ss), 1e-12f);
        #pragma unroll
        for (int j = 0; j < 16; j++) buf2[e * PS + j] = (__bf16)(prod[j] * inv);
        const float4* ep = (const float4*)(ea + (size_t)eid_reg * ED);
        #pragma unroll
        for (int j = 0; j < 4; j++) {
            float4 v = ep[j];
            bf16x4 bv = {(__bf16)v.x, (__bf16)v.y, (__bf16)v.z, (__bf16)v.w};
            *(bf16x4*)&buf2[e * PS + 16 + j * 4] = bv;
        }
    }
    __syncthreads();

    const bf16x8* pw1v  = (const bf16x8*)pw1;
    const bf16x8* pw2v  = (const bf16x8*)pw2;
    const bf16x8* pwc1v = (const bf16x8*)pwc1;
    const bf16x8* pwc2v = (const bf16x8*)pwc2;

    // ---- e1: K=32 (kt=8 of pw1) + presum (bias already in presum) ----
    f32x4 acc1[4][2];
    #pragma unroll
    for (int m = 0; m < 4; m++)
        #pragma unroll
        for (int n = 0; n < 2; n++) acc1[m][n] = (f32x4){0,0,0,0};
    {
        bf16x8 x1[4];
        #pragma unroll
        for (int m = 0; m < 4; m++)
            x1[m] = *(const bf16x8*)&buf2[(m*16 + c) * PS + quad*8];
        #pragma unroll
        for (int n = 0; n < 2; n++) {
            bf16x8 w = pw1v[((2*wave + n)*9 + 8)*64 + lane];
            #pragma unroll
            for (int m = 0; m < 4; m++)
                acc1[m][n] = __builtin_amdgcn_mfma_f32_16x16x32_bf16(w, x1[m], acc1[m][n], 0, 0, 0);
        }
    }
    #pragma unroll
    for (int n = 0; n < 2; n++) {
        int nt = 2*wave + n;
        #pragma unroll
        for (int m = 0; m < 4; m++) {
            int row = m*16 + c;
            bf16x4 p = *(const bf16x4*)&buf1[row * MS + nt*16 + quad*4];
            bf16x4 o = { (__bf16)fmaxf(acc1[m][n][0] + (float)p[0], 0.f),
                         (__bf16)fmaxf(acc1[m][n][1] + (float)p[1], 0.f),
                         (__bf16)fmaxf(acc1[m][n][2] + (float)p[2], 0.f),
                         (__bf16)fmaxf(acc1[m][n][3] + (float)p[3], 0.f) };
            *(bf16x4*)&buf1[row * MS + nt*16 + quad*4] = o;
        }
    }
    __syncthreads();

    // ---- e2: h1 @ We2 -> ef (buf2, stride MS) ----
    f32x4 acc2[4][2];
    #pragma unroll
    for (int m = 0; m < 4; m++)
        #pragma unroll
        for (int n = 0; n < 2; n++) acc2[m][n] = (f32x4){0,0,0,0};
    for (int kt = 0; kt < 4; kt++) {
        bf16x8 x[4];
        #pragma unroll
        for (int m = 0; m < 4; m++)
            x[m] = *(const bf16x8*)&buf1[(m*16 + c) * MS + kt*32 + quad*8];
        #pragma unroll
        for (int n = 0; n < 2; n++) {
            bf16x8 w = pw2v[((2*wave + n)*4 + kt)*64 + lane];
            #pragma unroll
            for (int m = 0; m < 4; m++)
                acc2[m][n] = __builtin_amdgcn_mfma_f32_16x16x32_bf16(w, x[m], acc2[m][n], 0, 0, 0);
        }
    }
    #pragma unroll
    for (int n = 0; n < 2; n++) {
        int nt = 2*wave + n;
        float4 bb = *(const float4*)&be2[nt*16 + quad*4];
        #pragma unroll
        for (int m = 0; m < 4; m++) {
            int row = m*16 + c;
            bf16x4 o = { (__bf16)fmaxf(acc2[m][n][0] + bb.x, 0.f),
                         (__bf16)fmaxf(acc2[m][n][1] + bb.y, 0.f),
                         (__bf16)fmaxf(acc2[m][n][2] + bb.z, 0.f),
                         (__bf16)fmaxf(acc2[m][n][3] + bb.w, 0.f) };
            *(bf16x4*)&buf2[row * MS + nt*16 + quad*4] = o;
        }
    }
    __syncthreads();   // buf2 (ef) stable from here on — nothing writes it again

    // ---- c1: ef @ Wc1 -> buf1 ----
    f32x4 acc3[4][2];
    #pragma unroll
    for (int m = 0; m < 4; m++)
        #pragma unroll
        for (int n = 0; n < 2; n++) acc3[m][n] = (f32x4){0,0,0,0};
    for (int kt = 0; kt < 4; kt++) {
        bf16x8 x[4];
        #pragma unroll
        for (int m = 0; m < 4; m++)
            x[m] = *(const bf16x8*)&buf2[(m*16 + c) * MS + kt*32 + quad*8];
        #pragma unroll
        for (int n = 0; n < 2; n++) {
            bf16x8 w = pwc1v[((2*wave + n)*4 + kt)*64 + lane];
            #pragma unroll
            for (int m = 0; m < 4; m++)
                acc3[m][n] = __builtin_amdgcn_mfma_f32_16x16x32_bf16(w, x[m], acc3[m][n], 0, 0, 0);
        }
    }
    #pragma unroll
    for (int n = 0; n < 2; n++) {
        int nt = 2*wave + n;
        float4 bb = *(const float4*)&bc1[nt*16 + quad*4];
        #pragma unroll
        for (int m = 0; m < 4; m++) {
            int row = m*16 + c;
            bf16x4 o = { (__bf16)fmaxf(acc3[m][n][0] + bb.x, 0.f),
                         (__bf16)fmaxf(acc3[m][n][1] + bb.y, 0.f),
                         (__bf16)fmaxf(acc3[m][n][2] + bb.z, 0.f),
                         (__bf16)fmaxf(acc3[m][n][3] + bb.w, 0.f) };
            *(bf16x4*)&buf1[row * MS + nt*16 + quad*4] = o;
        }
    }
    __syncthreads();

    // ---- c2: wave owns m-tile = wave (edges wave*16..+15) ----
    f32x4 accw = (f32x4){0,0,0,0};
    for (int kt = 0; kt < 4; kt++) {
        bf16x8 x = *(const bf16x8*)&buf1[(wave*16 + c) * MS + kt*32 + quad*8];
        accw = __builtin_amdgcn_mfma_f32_16x16x32_bf16(pwc2v[kt*64 + lane], x, accw, 0, 0, 0);
    }
    if (quad == 0) {
        int e = wave*16 + c;
        #pragma unroll
        for (int j = 0; j < 12; j++)
            cds[e][j] = (__bf16)((float)cds[e][j] * accw[j/3]);
    }

    // ---- agg_h seg-reduce (reads only buf2 — no barrier needed; runs while
    //      other waves finish c2) ----
    {
        float* aggh_b = agg_h + (size_t)b * NN_ * HID;
        const int col = t & 127, seg = t >> 7;    // 2 segs x 32 edges
        float run = 0.f;
        int cur = rs[seg * 32];
        for (int e = seg * 32; e < seg * 32 + 32; e++) {
            int r = rs[e];
            float v = (float)buf2[e * MS + col];
            if (r != cur) {
                atomicAdd(&aggh_b[(size_t)cur * HID + col], run);
                run = 0.f; cur = r;
            }
            run += v;
        }
        atomicAdd(&aggh_b[(size_t)cur * HID + col], run);
    }
    __syncthreads();   // cds updates visible

    if (t < 24) {
        float* aggc_b = agg_c + (size_t)b * NN_ * 12;
        const int j = t % 12, q = t / 12;         // 2 segs x 32 edges
        float run = 0.f;
        int cur = rs[q * 32];
        for (int e = q * 32; e < q * 32 + 32; e++) {
            int r = rs[e];
            float v = (float)cds[e][j];
            if (r != cur) {
                atomicAdd(&aggc_b[(size_t)cur * 12 + j], run);
                run = 0.f; cur = r;
            }
            run += v;
        }
        atomicAdd(&aggc_b[(size_t)cur * 12 + j], run);
    }
}

// ------- node kernel: MFMA bf16 MLP + residual + fused coord update -------
__global__ __launch_bounds__(256) void node_kernel(
    const float* __restrict__ h, const float* __restrict__ agg_h,
    const float* __restrict__ agg_c, const float* __restrict__ coord,
    const int* __restrict__ csr_off,
    const __bf16* __restrict__ pwn1, const float* __restrict__ bn1,
    const __bf16* __restrict__ pwn2, const float* __restrict__ bn2,
    float* __restrict__ out_h, float* __restrict__ out_c)
{
    __shared__ __align__(16) __bf16 zs[NPB2 * ZS];   // reused as os (fp32, stride 132)
    __shared__ __align__(16) __bf16 h1s[NPB2 * HS];
    const int t = threadIdx.x;
    const int b = blockIdx.y;
    const int n0 = blockIdx.x * NPB2;
    const int lane = t & 63, wave = t >> 6;
    const int quad = lane >> 4, c = lane & 15;

    #pragma unroll
    for (int it = 0; it < 8; it++) {
        int idx = it * 256 + t;              // 0..2047
        int node = idx >> 6, ch = idx & 63;  // ch 0..31 = h, 32..63 = agg_h
        int gn = n0 + node;
        float4 v = (float4){0.f, 0.f, 0.f, 0.f};
        if (gn < NN_) {
            const float* src = (ch < 32) ? &h[((size_t)b * NN_ + gn) * F + ch * 4]
                                         : &agg_h[((size_t)b * NN_ + gn) * HID + (ch - 32) * 4];
            v = *(const float4*)src;
        }
        bf16x4 bv = {(__bf16)v.x, (__bf16)v.y, (__bf16)v.z, (__bf16)v.w};
        *(bf16x4*)&zs[node * ZS + ch * 4] = bv;
    }
    __syncthreads();

    const bf16x8* w1v = (const bf16x8*)pwn1;
    const bf16x8* w2v = (const bf16x8*)pwn2;
    f32x4 a1[2][2];
    #pragma unroll
    for (int m = 0; m < 2; m++)
        #pragma unroll
        for (int n = 0; n < 2; n++) a1[m][n] = (f32x4){0,0,0,0};
    for (int kt = 0; kt < 8; kt++) {
        bf16x8 x[2];
        #pragma unroll
        for (int m = 0; m < 2; m++)
            x[m] = *(const bf16x8*)&zs[(m*16 + c) * ZS + kt*32 + quad*8];
        #pragma unroll
        for (int n = 0; n < 2; n++) {
            bf16x8 w = w1v[((2*wave + n)*8 + kt)*64 + lane];
            #pragma unroll
            for (int m = 0; m < 2; m++)
                a1[m][n] = __builtin_amdgcn_mfma_f32_16x16x32_bf16(w, x[m], a1[m][n], 0, 0, 0);
        }
    }
    __syncthreads();
    #pragma unroll
    for (int n = 0; n < 2; n++) {
        int nt = 2*wave + n;
        float4 bb = *(const float4*)&bn1[nt*16 + quad*4];
        #pragma unroll
        for (int m = 0; m < 2; m++) {
            bf16x4 o = { (__bf16)fmaxf(a1[m][n][0] + bb.x, 0.f),
                         (__bf16)fmaxf(a1[m][n][1] + bb.y, 0.f),
                         (__bf16)fmaxf(a1[m][n][2] + bb.z, 0.f),
                         (__bf16)fmaxf(a1[m][n][3] + bb.w, 0.f) };
            *(bf16x4*)&h1s[(m*16 + c) * HS + nt*16 + quad*4] = o;
        }
    }
    __syncthreads();

    f32x4 a2[2][2];
    #pragma unroll
    for (int m = 0; m < 2; m++)
        #pragma unroll
        for (int n = 0; n < 2; n++) a2[m][n] = (f32x4){0,0,0,0};
    for (int kt = 0; kt < 4; kt++) {
        bf16x8 x[2];
        #pragma unroll
        for (int m = 0; m < 2; m++)
            x[m] = *(const bf16x8*)&h1s[(m*16 + c) * HS + kt*32 + quad*8];
        #pragma unroll
        for (int n = 0; n < 2; n++) {
            bf16x8 w = w2v[((2*wave + n)*4 + kt)*64 + lane];
            #pragma unroll
            for (int m = 0; m < 2; m++)
                a2[m][n] = __builtin_amdgcn_mfma_f32_16x16x32_bf16(w, x[m], a2[m][n], 0, 0, 0);
        }
    }
    float* os = (float*)zs;   // stride 132 floats
    #pragma unroll
    for (int n = 0; n < 2; n++) {
        int nt = 2*wave + n;
        float4 bb = *(const float4*)&bn2[nt*16 + quad*4];
        #pragma unroll
        for (int m = 0; m < 2; m++) {
            f32x4 o = { a2[m][n][0] + bb.x, a2[m][n][1] + bb.y,
                        a2[m][n][2] + bb.z, a2[m][n][3] + bb.w };
            *(f32x4*)&os[(m*16 + c) * 132 + nt*16 + quad*4] = o;
        }
    }
    __syncthreads();

    #pragma unroll
    for (int it = 0; it < 4; it++) {
        int idx = it * 256 + t;              // 0..1023
        int node = idx >> 5, ch = idx & 31;
        int gn = n0 + node;
        if (gn < NN_) {
            size_t gb = ((size_t)b * NN_ + gn) * F + ch * 4;
            float4 hres = *(const float4*)&h[gb];
            float4 acc = *(const float4*)&os[node * 132 + ch * 4];
            float4 o = { hres.x + acc.x, hres.y + acc.y, hres.z + acc.z, hres.w + acc.w };
            *(float4*)&out_h[gb] = o;
        }
    }
    for (int idx = t; idx < NPB2 * 12; idx += 256) {
        int node = idx / 12, j = idx % 12;
        int gn = n0 + node;
        if (gn < NN_) {
            float deg = (float)(csr_off[gn + 1] - csr_off[gn]);
            size_t ci = ((size_t)b * NN_ + gn) * 12 + j;
            out_c[ci] = coord[ci] + agg_c[ci] / fmaxf(deg, 1.0f);
        }
    }
}

extern "C" void kernel_launch(void* const* d_in, const int* in_sizes, int n_in,
                              void* d_out, int out_size, void* d_ws, size_t ws_size,
                              hipStream_t stream) {
    const float* h     = (const float*)d_in[0];
    const float* coord = (const float*)d_in[1];
    const int*   ei    = (const int*)d_in[2];
    const float* ea    = (const float*)d_in[3];
    const float* We1   = (const float*)d_in[4];
    const float* be1   = (const float*)d_in[5];
    const float* We2   = (const float*)d_in[6];
    const float* be2   = (const float*)d_in[7];
    const float* Wn1   = (const float*)d_in[8];
    const float* bn1   = (const float*)d_in[9];
    const float* Wn2   = (const float*)d_in[10];
    const float* bn2   = (const float*)d_in[11];
    const float* Wc1   = (const float*)d_in[12];
    const float* bc1   = (const float*)d_in[13];
    const float* Wc2   = (const float*)d_in[14];

    float* out_h = (float*)d_out;                       // [B,N,F]
    float* out_c = out_h + (size_t)B * NN_ * F;         // [B,N,4,3]

    unsigned char* base = (unsigned char*)d_ws;
    __bf16* pw1  = (__bf16*)base;             // 36864 bf16
    __bf16* pw2  = pw1 + 36864;               // 16384
    __bf16* pwc1 = pw2 + 16384;               // 16384
    __bf16* pwc2 = pwc1 + 16384;              // 2048
    __bf16* pwn1 = pwc2 + 2048;               // 32768
    __bf16* pwn2 = pwn1 + 32768;              // 16384  -> 120832 elems = 241664 B
    unsigned char* dyn = base + 241664;

    int* csr_cnt = (int*)(dyn);               // 20000 B
    int* csr_off = (int*)(dyn + 20000);       // 20016 B
    int* csr_pos = (int*)(dyn + 40016);       // 20000 B
    int* bucket  = (int*)(dyn + 60016);       // 640000 B
    float* agg_h = (float*)(dyn + 700016);    // [B,N,HID]  5,120,000 B
    float* agg_c = agg_h + (size_t)B * NN_ * HID;      // [B,N,12] 480,000 B
    __bf16* pr   = (__bf16*)(agg_c + (size_t)B * NN_ * 12);  // 2,560,000 B
    __bf16* pc   = pr + (size_t)B * NN_ * F;                 // 2,560,000 B

    hipMemsetAsync(csr_cnt, 0, 20000, stream);

    pack_hist_kernel<<<472 + 625, 256, 0, stream>>>(We1, We2, Wc1, Wc2, Wn1, Wn2, ei,
                                                    pw1, pw2, pwc1, pwc2, pwn1, pwn2,
                                                    (float4*)agg_h, csr_cnt);

    scan_kernel<<<1, 512, 0, stream>>>(csr_cnt, csr_off, csr_pos);

    mid_kernel<<<NBUCKET + 80, 512, 0, stream>>>(ei, csr_pos, bucket, h, pw1, be1, pr, pc);

    dim3 eg(NE_ / EDG, B);   // 2500 x 2
    edge_kernel<<<eg, 256, 0, stream>>>(pr, pc, coord, ei, ea, bucket, be2, bc1,
                                        pw1, pw2, pwc1, pwc2, agg_h, agg_c);

    dim3 ng((NN_ + NPB2 - 1) / NPB2, B);   // 157 x 2
    node_kernel<<<ng, 256, 0, stream>>>(h, agg_h, agg_c, coord, csr_off,
                                        pwn1, bn1, pwn2, bn2, out_h, out_c);
}